// Round 4
// baseline (517.699 us; speedup 1.0000x reference)
//
#include <hip/hip_runtime.h>
#include <hip/hip_bf16.h>

typedef __attribute__((ext_vector_type(8))) short short8;
typedef __attribute__((ext_vector_type(4))) short short4v;
typedef __attribute__((ext_vector_type(4))) float f32x4;

static __device__ __forceinline__ unsigned short f2bf(float f) {
  unsigned int u = __float_as_uint(f);
  u += 0x7fffu + ((u >> 16) & 1u);
  return (unsigned short)(u >> 16);
}

static __device__ __forceinline__ unsigned pk2bf(float a, float b) {
  union { __hip_bfloat162 h; unsigned u; } v;
  v.h = __float22bfloat162_rn(make_float2(a, b));
  return v.u;
}

// ---------------- converts ----------------
__global__ void conv_bf16_kernel(const float* __restrict__ in,
                                 unsigned short* __restrict__ out, int n) {
  int i = (blockIdx.x * blockDim.x + threadIdx.x) * 4;
  if (i >= n) return;
  float4 v = *(const float4*)(in + i);
  short4v o;
  o[0] = (short)f2bf(v.x); o[1] = (short)f2bf(v.y);
  o[2] = (short)f2bf(v.z); o[3] = (short)f2bf(v.w);
  *(short4v*)(out + i) = o;
}

// W [K=1024,N=1024] fp32 -> Wt [N,K] bf16
__global__ void wtrans_kernel(const float* __restrict__ W,
                              unsigned short* __restrict__ Wt) {
  __shared__ float t[32][33];
  int n0 = blockIdx.x * 32, k0 = blockIdx.y * 32;
#pragma unroll
  for (int j = 0; j < 4; ++j)
    t[threadIdx.y + j * 8][threadIdx.x] =
        W[(size_t)(k0 + threadIdx.y + j * 8) * 1024 + n0 + threadIdx.x];
  __syncthreads();
#pragma unroll
  for (int j = 0; j < 4; ++j)
    Wt[(size_t)(n0 + threadIdx.y + j * 8) * 1024 + k0 + threadIdx.x] =
        f2bf(t[threadIdx.x][threadIdx.y + j * 8]);
}

__global__ void mask_kernel(const float* __restrict__ e, float* __restrict__ mb, int n) {
  int i = blockIdx.x * blockDim.x + threadIdx.x;
  if (i < n) mb[i] = (fabsf(e[i]) > 0.1f) ? 0.0f : -1e30f;
}

// ---------------- GEMM: C[M=8192,N=1024] = X @ Wt^T + bias ----------------
template <int MODE>
__global__ __launch_bounds__(256) void gemm128_kernel(
    const unsigned short* __restrict__ X, const unsigned short* __restrict__ Wt,
    const float* __restrict__ bias, void* __restrict__ outp) {
  const int K = 1024;
  __shared__ unsigned short Al[128 * 40];
  __shared__ unsigned short Bl[128 * 40];
  const int m0 = blockIdx.x * 128, n0 = blockIdx.y * 128;
  const int tid = threadIdx.x, lane = tid & 63, wid = tid >> 6;
  const int wr = wid >> 1, wc = wid & 1;
  const int g = lane >> 4, lr = lane & 15;
  const f32x4 fz = {0.f, 0.f, 0.f, 0.f};
  f32x4 acc[4][4];
#pragma unroll
  for (int i = 0; i < 4; i++)
#pragma unroll
    for (int j = 0; j < 4; j++) acc[i][j] = fz;
  const int srow = tid >> 2;
  const int skc = (tid & 3) * 8;

  for (int k0 = 0; k0 < K; k0 += 32) {
#pragma unroll
    for (int p = 0; p < 2; ++p) {
      int row = srow + p * 64;
      *(short8*)(Al + row * 40 + skc) =
          *(const short8*)(X + (size_t)(m0 + row) * K + k0 + skc);
      *(short8*)(Bl + row * 40 + skc) =
          *(const short8*)(Wt + (size_t)(n0 + row) * K + k0 + skc);
    }
    __syncthreads();
    short8 a[4], b[4];
#pragma unroll
    for (int i = 0; i < 4; i++)
      a[i] = *(const short8*)(Al + (wr * 64 + i * 16 + lr) * 40 + g * 8);
#pragma unroll
    for (int i = 0; i < 4; i++)
      b[i] = *(const short8*)(Bl + (wc * 64 + i * 16 + lr) * 40 + g * 8);
#pragma unroll
    for (int i = 0; i < 4; i++)
#pragma unroll
      for (int j = 0; j < 4; j++)
        acc[i][j] = __builtin_amdgcn_mfma_f32_16x16x32_bf16(a[i], b[j], acc[i][j], 0, 0, 0);
    __syncthreads();
  }

#pragma unroll
  for (int i = 0; i < 4; i++) {
    const int mrow0 = m0 + wr * 64 + i * 16 + g * 4;
#pragma unroll
    for (int j = 0; j < 4; j++) {
      const int ncol = n0 + wc * 64 + j * 16 + lr;
      const float bv = bias[ncol];
      if (MODE == 2) {
        float* out = (float*)outp;
#pragma unroll
        for (int e = 0; e < 4; e++)
          out[(size_t)(mrow0 + e) * 1024 + ncol] = acc[i][j][e] + bv;
      } else if (MODE == 0) {
        unsigned short* out = (unsigned short*)outp;
        const int h = ncol >> 6, dh = ncol & 63;
#pragma unroll
        for (int e = 0; e < 4; e++) {
          int mrow = mrow0 + e;
          int b_ = mrow >> 11, l = mrow & 2047;
          out[((size_t)(b_ * 16 + h) * 2048 + l) * 64 + dh] = f2bf(acc[i][j][e] + bv);
        }
      } else {
        unsigned short* out = (unsigned short*)outp;
        const int h = ncol >> 6, d = ncol & 63;
        const int b_ = mrow0 >> 11, s = mrow0 & 2047;
        short4v pk;
#pragma unroll
        for (int e = 0; e < 4; e++) pk[e] = (short)f2bf(acc[i][j][e] + bv);
        *(short4v*)(out + ((size_t)(b_ * 16 + h) * 64 + d) * 2048 + s) = pk;
      }
    }
  }
}

// ---------------- flash attention v4: barrier-free, LDS-free, L1-shared ----------------
// Qh,Kh: [B,H,S,64] bf16; Vt: [B,H,64,S] bf16; mb: [B,S] fp32 bias (0/-1e30)
// AO: [B*L, 1024] bf16.
// Grid: 512 blocks x 512 thr (8 waves). All 8 waves of a block share one bh and
// stream the same K/V tiles (16KB) nearly in lockstep -> L1 serves 7/8 of reads.
// No __syncthreads, no LDS, no online max (masked-bias scores bounded),
// denominator reduced once in the epilogue. 32 q-rows per wave -> 4096 waves.
__global__ __launch_bounds__(512, 4) void attn_kernel(
    const unsigned short* __restrict__ Qh, const unsigned short* __restrict__ Kh,
    const unsigned short* __restrict__ Vt, const float* __restrict__ mb,
    unsigned short* __restrict__ AO) {
  const int S = 2048;
  // XCD-chunked bijective swizzle: 512 blocks = 8 XCDs x 64; each XCD owns
  // 8 bh (4MB K/V = its L2).
  int bx = blockIdx.x;
  int lid = (bx & 7) * 64 + (bx >> 3);
  const int bh = lid >> 3, qbb = lid & 7;
  const int b_ = bh >> 4, h = bh & 15;
  const unsigned short* Qp = Qh + (size_t)bh * S * 64;
  const unsigned short* Kp = Kh + (size_t)bh * S * 64;
  const unsigned short* Vp = Vt + (size_t)bh * 64 * S;
  const float* mbp = mb + b_ * S;
  const int tid = threadIdx.x, lane = tid & 63, wid = tid >> 6;
  const int g = lane >> 4, lr = lane & 15;
  const int qbase = qbb * 256 + wid * 32;
  const float c2 = 0.18033688011f;  // log2(e) / sqrt(64)
  const f32x4 fz = {0.f, 0.f, 0.f, 0.f};

  short8 qf[2][2];
#pragma unroll
  for (int qt = 0; qt < 2; qt++)
#pragma unroll
    for (int kh = 0; kh < 2; kh++)
      qf[qt][kh] = *(const short8*)(Qp + (size_t)(qbase + qt * 16 + lr) * 64 + kh * 32 + g * 8);

  f32x4 o[2][4];
  f32x4 psum[2];
#pragma unroll
  for (int qt = 0; qt < 2; qt++) {
    psum[qt] = fz;
#pragma unroll
    for (int t = 0; t < 4; t++) o[qt][t] = fz;
  }

  for (int s0 = 0; s0 < S; s0 += 64) {
    // K fragments: 8 x 16B loads (L1/L2-resident)
    short8 kf[4][2];
#pragma unroll
    for (int st = 0; st < 4; st++)
#pragma unroll
      for (int kh = 0; kh < 2; kh++)
        kf[st][kh] = *(const short8*)(Kp + (size_t)(s0 + st * 16 + lr) * 64 + kh * 32 + g * 8);
    // V^T fragments: 16 x 8B loads
    short8 vf[4][2];
#pragma unroll
    for (int tt = 0; tt < 4; tt++)
#pragma unroll
      for (int ks = 0; ks < 2; ks++) {
        const unsigned short* base = Vp + (size_t)(tt * 16 + lr) * S + s0 + ks * 32;
        short4v lo = *(const short4v*)(base + g * 4);
        short4v hi = *(const short4v*)(base + 16 + g * 4);
        short8 v;
        v[0] = lo[0]; v[1] = lo[1]; v[2] = lo[2]; v[3] = lo[3];
        v[4] = hi[0]; v[5] = hi[1]; v[6] = hi[2]; v[7] = hi[3];
        vf[tt][ks] = v;
      }
    f32x4 mbv[4];
#pragma unroll
    for (int st = 0; st < 4; st++)
      mbv[st] = *(const f32x4*)(mbp + s0 + st * 16 + g * 4);

#pragma unroll
    for (int qt = 0; qt < 2; qt++) {
      f32x4 sc[4];
#pragma unroll
      for (int st = 0; st < 4; st++) {
        f32x4 a0 = __builtin_amdgcn_mfma_f32_16x16x32_bf16(kf[st][0], qf[qt][0], fz, 0, 0, 0);
        sc[st] = __builtin_amdgcn_mfma_f32_16x16x32_bf16(kf[st][1], qf[qt][1], a0, 0, 0, 0);
      }
      f32x4 pv[4];
#pragma unroll
      for (int st = 0; st < 4; st++) {
        f32x4 x = sc[st] * c2 + mbv[st];
#pragma unroll
        for (int e = 0; e < 4; e++) pv[st][e] = exp2f(x[e]);
      }
      psum[qt] += (pv[0] + pv[1]) + (pv[2] + pv[3]);
      union { short8 s8; unsigned u[4]; } pk0, pk1;
      pk0.u[0] = pk2bf(pv[0][0], pv[0][1]); pk0.u[1] = pk2bf(pv[0][2], pv[0][3]);
      pk0.u[2] = pk2bf(pv[1][0], pv[1][1]); pk0.u[3] = pk2bf(pv[1][2], pv[1][3]);
      pk1.u[0] = pk2bf(pv[2][0], pv[2][1]); pk1.u[1] = pk2bf(pv[2][2], pv[2][3]);
      pk1.u[2] = pk2bf(pv[3][0], pv[3][1]); pk1.u[3] = pk2bf(pv[3][2], pv[3][3]);
#pragma unroll
      for (int tt = 0; tt < 4; tt++) {
        o[qt][tt] = __builtin_amdgcn_mfma_f32_16x16x32_bf16(vf[tt][0], pk0.s8, o[qt][tt], 0, 0, 0);
        o[qt][tt] = __builtin_amdgcn_mfma_f32_16x16x32_bf16(vf[tt][1], pk1.s8, o[qt][tt], 0, 0, 0);
      }
    }
  }

#pragma unroll
  for (int qt = 0; qt < 2; qt++) {
    float l = (psum[qt][0] + psum[qt][1]) + (psum[qt][2] + psum[qt][3]);
    l += __shfl_xor(l, 16);
    l += __shfl_xor(l, 32);
    float inv = l > 0.f ? 1.f / l : 0.f;
    size_t row = (size_t)b_ * 2048 + qbase + qt * 16 + lr;
#pragma unroll
    for (int tt = 0; tt < 4; tt++) {
      short4v pkv;
#pragma unroll
      for (int i = 0; i < 4; i++) pkv[i] = (short)f2bf(o[qt][tt][i] * inv);
      *(short4v*)(AO + row * 1024 + h * 64 + tt * 16 + g * 4) = pkv;
    }
  }
}

// ---------------- launch ----------------
extern "C" void kernel_launch(void* const* d_in, const int* in_sizes, int n_in,
                              void* d_out, int out_size, void* d_ws, size_t ws_size,
                              hipStream_t stream) {
  const float* q_x = (const float*)d_in[0];
  const float* k_x = (const float*)d_in[1];
  const float* v_x = (const float*)d_in[2];
  const float* energy = (const float*)d_in[3];
  const float* Wq = (const float*)d_in[4];
  const float* bq = (const float*)d_in[5];
  const float* Wk = (const float*)d_in[6];
  const float* bk = (const float*)d_in[7];
  const float* Wv = (const float*)d_in[8];
  const float* bv = (const float*)d_in[9];
  const float* Wo = (const float*)d_in[10];
  const float* bo = (const float*)d_in[11];

  char* w = (char*)d_ws;
  auto take = [&](size_t bytes) {
    char* p = w;
    w += (bytes + 255) & ~(size_t)255;
    return p;
  };
  const size_t XB = (size_t)8192 * 1024 * 2;
  unsigned short* Xq = (unsigned short*)take(XB);
  unsigned short* Xk = (unsigned short*)take(XB);
  unsigned short* Xv = (unsigned short*)take(XB);
  unsigned short* Wtq = (unsigned short*)take((size_t)1024 * 1024 * 2);
  unsigned short* Wtk = (unsigned short*)take((size_t)1024 * 1024 * 2);
  unsigned short* Wtv = (unsigned short*)take((size_t)1024 * 1024 * 2);
  unsigned short* Wto = (unsigned short*)take((size_t)1024 * 1024 * 2);
  float* mb = (float*)take((size_t)4 * 2048 * 4);
  unsigned short* Qh = (unsigned short*)take(XB);
  unsigned short* Kh = (unsigned short*)take(XB);
  unsigned short* Vt = (unsigned short*)take(XB);
  unsigned short* AO = (unsigned short*)take(XB);

  const int NX = 8192 * 1024;
  conv_bf16_kernel<<<NX / 1024, 256, 0, stream>>>(q_x, Xq, NX);
  conv_bf16_kernel<<<NX / 1024, 256, 0, stream>>>(k_x, Xk, NX);
  conv_bf16_kernel<<<NX / 1024, 256, 0, stream>>>(v_x, Xv, NX);
  wtrans_kernel<<<dim3(32, 32), dim3(32, 8), 0, stream>>>(Wq, Wtq);
  wtrans_kernel<<<dim3(32, 32), dim3(32, 8), 0, stream>>>(Wk, Wtk);
  wtrans_kernel<<<dim3(32, 32), dim3(32, 8), 0, stream>>>(Wv, Wtv);
  wtrans_kernel<<<dim3(32, 32), dim3(32, 8), 0, stream>>>(Wo, Wto);
  mask_kernel<<<32, 256, 0, stream>>>(energy, mb, 8192);

  gemm128_kernel<0><<<dim3(64, 8), 256, 0, stream>>>(Xq, Wtq, bq, (void*)Qh);
  gemm128_kernel<0><<<dim3(64, 8), 256, 0, stream>>>(Xk, Wtk, bk, (void*)Kh);
  gemm128_kernel<1><<<dim3(64, 8), 256, 0, stream>>>(Xv, Wtv, bv, (void*)Vt);
  attn_kernel<<<512, 512, 0, stream>>>(Qh, Kh, Vt, mb, AO);
  gemm128_kernel<2><<<dim3(64, 8), 256, 0, stream>>>(AO, Wto, bo, d_out);
}

// Round 5
// 282.659 us; speedup vs baseline: 1.8315x; 1.8315x over previous
//
#include <hip/hip_runtime.h>
#include <hip/hip_bf16.h>

typedef __attribute__((ext_vector_type(8))) short short8;
typedef __attribute__((ext_vector_type(4))) short short4v;
typedef __attribute__((ext_vector_type(4))) float f32x4;

static __device__ __forceinline__ unsigned short f2bf(float f) {
  unsigned int u = __float_as_uint(f);
  u += 0x7fffu + ((u >> 16) & 1u);
  return (unsigned short)(u >> 16);
}

static __device__ __forceinline__ unsigned pk2bf(float a, float b) {
  union { __hip_bfloat162 h; unsigned u; } v;
  v.h = __float22bfloat162_rn(make_float2(a, b));
  return v.u;
}

static __device__ __forceinline__ void gload_lds16(const unsigned short* g,
                                                   unsigned short* l) {
  __builtin_amdgcn_global_load_lds((const __attribute__((address_space(1))) void*)g,
                                   (__attribute__((address_space(3))) void*)l, 16, 0, 0);
}

// ---------------- converts ----------------
__global__ void conv_bf16_kernel(const float* __restrict__ in,
                                 unsigned short* __restrict__ out, int n) {
  int i = (blockIdx.x * blockDim.x + threadIdx.x) * 4;
  if (i >= n) return;
  float4 v = *(const float4*)(in + i);
  short4v o;
  o[0] = (short)f2bf(v.x); o[1] = (short)f2bf(v.y);
  o[2] = (short)f2bf(v.z); o[3] = (short)f2bf(v.w);
  *(short4v*)(out + i) = o;
}

// W [K=1024,N=1024] fp32 -> Wt [N,K] bf16
__global__ void wtrans_kernel(const float* __restrict__ W,
                              unsigned short* __restrict__ Wt) {
  __shared__ float t[32][33];
  int n0 = blockIdx.x * 32, k0 = blockIdx.y * 32;
#pragma unroll
  for (int j = 0; j < 4; ++j)
    t[threadIdx.y + j * 8][threadIdx.x] =
        W[(size_t)(k0 + threadIdx.y + j * 8) * 1024 + n0 + threadIdx.x];
  __syncthreads();
#pragma unroll
  for (int j = 0; j < 4; ++j)
    Wt[(size_t)(n0 + threadIdx.y + j * 8) * 1024 + k0 + threadIdx.x] =
        f2bf(t[threadIdx.x][threadIdx.y + j * 8]);
}

__global__ void mask_kernel(const float* __restrict__ e, float* __restrict__ mb, int n) {
  int i = blockIdx.x * blockDim.x + threadIdx.x;
  if (i < n) mb[i] = (fabsf(e[i]) > 0.1f) ? 0.0f : -1e30f;
}

// ---------------- GEMM: C[M=8192,N=1024] = X @ Wt^T + bias ----------------
template <int MODE>
__global__ __launch_bounds__(256) void gemm128_kernel(
    const unsigned short* __restrict__ X, const unsigned short* __restrict__ Wt,
    const float* __restrict__ bias, void* __restrict__ outp) {
  const int K = 1024;
  __shared__ unsigned short Al[128 * 40];
  __shared__ unsigned short Bl[128 * 40];
  const int m0 = blockIdx.x * 128, n0 = blockIdx.y * 128;
  const int tid = threadIdx.x, lane = tid & 63, wid = tid >> 6;
  const int wr = wid >> 1, wc = wid & 1;
  const int g = lane >> 4, lr = lane & 15;
  const f32x4 fz = {0.f, 0.f, 0.f, 0.f};
  f32x4 acc[4][4];
#pragma unroll
  for (int i = 0; i < 4; i++)
#pragma unroll
    for (int j = 0; j < 4; j++) acc[i][j] = fz;
  const int srow = tid >> 2;
  const int skc = (tid & 3) * 8;

  for (int k0 = 0; k0 < K; k0 += 32) {
#pragma unroll
    for (int p = 0; p < 2; ++p) {
      int row = srow + p * 64;
      *(short8*)(Al + row * 40 + skc) =
          *(const short8*)(X + (size_t)(m0 + row) * K + k0 + skc);
      *(short8*)(Bl + row * 40 + skc) =
          *(const short8*)(Wt + (size_t)(n0 + row) * K + k0 + skc);
    }
    __syncthreads();
    short8 a[4], b[4];
#pragma unroll
    for (int i = 0; i < 4; i++)
      a[i] = *(const short8*)(Al + (wr * 64 + i * 16 + lr) * 40 + g * 8);
#pragma unroll
    for (int i = 0; i < 4; i++)
      b[i] = *(const short8*)(Bl + (wc * 64 + i * 16 + lr) * 40 + g * 8);
#pragma unroll
    for (int i = 0; i < 4; i++)
#pragma unroll
      for (int j = 0; j < 4; j++)
        acc[i][j] = __builtin_amdgcn_mfma_f32_16x16x32_bf16(a[i], b[j], acc[i][j], 0, 0, 0);
    __syncthreads();
  }

#pragma unroll
  for (int i = 0; i < 4; i++) {
    const int mrow0 = m0 + wr * 64 + i * 16 + g * 4;
#pragma unroll
    for (int j = 0; j < 4; j++) {
      const int ncol = n0 + wc * 64 + j * 16 + lr;
      const float bv = bias[ncol];
      if (MODE == 2) {
        float* out = (float*)outp;
#pragma unroll
        for (int e = 0; e < 4; e++)
          out[(size_t)(mrow0 + e) * 1024 + ncol] = acc[i][j][e] + bv;
      } else if (MODE == 0) {
        unsigned short* out = (unsigned short*)outp;
        const int h = ncol >> 6, dh = ncol & 63;
#pragma unroll
        for (int e = 0; e < 4; e++) {
          int mrow = mrow0 + e;
          int b_ = mrow >> 11, l = mrow & 2047;
          out[((size_t)(b_ * 16 + h) * 2048 + l) * 64 + dh] = f2bf(acc[i][j][e] + bv);
        }
      } else {
        unsigned short* out = (unsigned short*)outp;
        const int h = ncol >> 6, d = ncol & 63;
        const int b_ = mrow0 >> 11, s = mrow0 & 2047;
        short4v pk;
#pragma unroll
        for (int e = 0; e < 4; e++) pk[e] = (short)f2bf(acc[i][j][e] + bv);
        *(short4v*)(out + ((size_t)(b_ * 16 + h) * 64 + d) * 2048 + s) = pk;
      }
    }
  }
}

// ---------------- flash attention v5: LDS double-buffer + global_load_lds prefetch ----
// Qh,Kh: [B,H,S,64] bf16; Vt: [B,H,64,S] bf16; mb: [B,S] fp32 bias (0/-1e30)
// AO: [B*L, 1024] bf16.
// Grid: 512 blocks x 512 thr (8 waves, 32 q-rows each => 256 q-rows/block).
// XCD-chunked swizzle: each XCD owns 8 bh -> 4MB K/V = its L2.
// K/V tiles (64 keys, 8KB each) staged via global_load_lds width-16 into a
// double buffer; tile t+1 issued before computing tile t (latency hidden).
// LDS linear dest + inverse-swizzled global source + XOR-swizzled ds_read
// (rule #21) kills the 128B-row bank conflict. No online max (bounded scores),
// denominator reduced once in epilogue.
__global__ __launch_bounds__(512, 4) void attn_kernel(
    const unsigned short* __restrict__ Qh, const unsigned short* __restrict__ Kh,
    const unsigned short* __restrict__ Vt, const float* __restrict__ mb,
    unsigned short* __restrict__ AO) {
  const int S = 2048;
  __shared__ unsigned short Lds[2][8192];  // [buf][ K:0..4095 | V:4096..8191 ]
  int bx = blockIdx.x;
  int lid = (bx & 7) * 64 + (bx >> 3);
  const int bh = lid >> 3, qbb = lid & 7;
  const int b_ = bh >> 4, h = bh & 15;
  const unsigned short* Qp = Qh + (size_t)bh * S * 64;
  const unsigned short* Kp = Kh + (size_t)bh * S * 64;
  const unsigned short* Vp = Vt + (size_t)bh * 64 * S;
  const float* mbp = mb + b_ * S;
  const int tid = threadIdx.x, lane = tid & 63, wid = tid >> 6;
  const int g = lane >> 4, lr = lane & 15;
  const int qbase = qbb * 256 + wid * 32;
  const float c2 = 0.18033688011f;  // log2(e) / sqrt(64)
  const f32x4 fz = {0.f, 0.f, 0.f, 0.f};

  // staging geometry (per wave): covers 1KB of K and 1KB of V per call
  const int srow = (lane >> 3);          // sub-row within wave's 8-row chunk
  const int schk = (lane & 7) ^ srow;    // inverse-swizzled source chunk
  const unsigned short* gK = Kp + (size_t)(wid * 8 + srow) * 64 + schk * 8;
  const unsigned short* gV = Vp + (size_t)(wid * 8 + srow) * S + schk * 8;

  short8 qf[2][2];
#pragma unroll
  for (int qt = 0; qt < 2; qt++)
#pragma unroll
    for (int kh = 0; kh < 2; kh++)
      qf[qt][kh] = *(const short8*)(Qp + (size_t)(qbase + qt * 16 + lr) * 64 + kh * 32 + g * 8);

  f32x4 o[2][4];
  f32x4 psum[2];
#pragma unroll
  for (int qt = 0; qt < 2; qt++) {
    psum[qt] = fz;
#pragma unroll
    for (int t = 0; t < 4; t++) o[qt][t] = fz;
  }

  // prologue: stage tile 0 into buf 0
  gload_lds16(gK, &Lds[0][wid * 512]);
  gload_lds16(gV, &Lds[0][4096 + wid * 512]);
  __syncthreads();

  const int s7 = lr & 7;
  int cur = 0;
  for (int t = 0; t < 32; ++t) {
    const int s0 = t * 64;
    if (t < 31) {  // prefetch next tile into other buffer
      gload_lds16(gK + (size_t)(s0 + 64) * 64, &Lds[cur ^ 1][wid * 512]);
      gload_lds16(gV + (s0 + 64), &Lds[cur ^ 1][4096 + wid * 512]);
    }
    const unsigned short* Kb = &Lds[cur][0];
    const unsigned short* Vb = &Lds[cur][4096];

    short8 kf[4][2];
#pragma unroll
    for (int st = 0; st < 4; st++)
#pragma unroll
      for (int kh = 0; kh < 2; kh++)
        kf[st][kh] = *(const short8*)(Kb + (st * 16 + lr) * 64 + (((kh * 4 + g) ^ s7) * 8));

    f32x4 mbv[4];
#pragma unroll
    for (int st = 0; st < 4; st++)
      mbv[st] = *(const f32x4*)(mbp + s0 + st * 16 + g * 4);

    union { unsigned u[8]; short8 s8[2]; } pk[2];
#pragma unroll
    for (int qt = 0; qt < 2; qt++) {
#pragma unroll
      for (int st = 0; st < 4; st++) {
        f32x4 a0 = __builtin_amdgcn_mfma_f32_16x16x32_bf16(kf[st][0], qf[qt][0], fz, 0, 0, 0);
        f32x4 s = __builtin_amdgcn_mfma_f32_16x16x32_bf16(kf[st][1], qf[qt][1], a0, 0, 0, 0);
        f32x4 x = s * c2 + mbv[st];
        f32x4 p;
#pragma unroll
        for (int e = 0; e < 4; e++) p[e] = exp2f(x[e]);
        psum[qt] += p;
        pk[qt].u[st * 2] = pk2bf(p[0], p[1]);
        pk[qt].u[st * 2 + 1] = pk2bf(p[2], p[3]);
      }
    }

#pragma unroll
    for (int tt = 0; tt < 4; tt++) {
      const unsigned short* vb = Vb + (tt * 16 + lr) * 64;
      short8 v0, v1;
      {
        short4v lo = *(const short4v*)(vb + (((g >> 1) ^ s7) * 8) + (g & 1) * 4);
        short4v hi = *(const short4v*)(vb + (((2 + (g >> 1)) ^ s7) * 8) + (g & 1) * 4);
        v0[0] = lo[0]; v0[1] = lo[1]; v0[2] = lo[2]; v0[3] = lo[3];
        v0[4] = hi[0]; v0[5] = hi[1]; v0[6] = hi[2]; v0[7] = hi[3];
      }
      {
        short4v lo = *(const short4v*)(vb + (((4 + (g >> 1)) ^ s7) * 8) + (g & 1) * 4);
        short4v hi = *(const short4v*)(vb + (((6 + (g >> 1)) ^ s7) * 8) + (g & 1) * 4);
        v1[0] = lo[0]; v1[1] = lo[1]; v1[2] = lo[2]; v1[3] = lo[3];
        v1[4] = hi[0]; v1[5] = hi[1]; v1[6] = hi[2]; v1[7] = hi[3];
      }
#pragma unroll
      for (int qt = 0; qt < 2; qt++) {
        o[qt][tt] = __builtin_amdgcn_mfma_f32_16x16x32_bf16(v0, pk[qt].s8[0], o[qt][tt], 0, 0, 0);
        o[qt][tt] = __builtin_amdgcn_mfma_f32_16x16x32_bf16(v1, pk[qt].s8[1], o[qt][tt], 0, 0, 0);
      }
    }
    __syncthreads();
    cur ^= 1;
  }

#pragma unroll
  for (int qt = 0; qt < 2; qt++) {
    float l = (psum[qt][0] + psum[qt][1]) + (psum[qt][2] + psum[qt][3]);
    l += __shfl_xor(l, 16);
    l += __shfl_xor(l, 32);
    float inv = l > 0.f ? 1.f / l : 0.f;
    size_t row = (size_t)b_ * 2048 + qbase + qt * 16 + lr;
#pragma unroll
    for (int tt = 0; tt < 4; tt++) {
      short4v pkv;
#pragma unroll
      for (int i = 0; i < 4; i++) pkv[i] = (short)f2bf(o[qt][tt][i] * inv);
      *(short4v*)(AO + row * 1024 + h * 64 + tt * 16 + g * 4) = pkv;
    }
  }
}

// ---------------- launch ----------------
extern "C" void kernel_launch(void* const* d_in, const int* in_sizes, int n_in,
                              void* d_out, int out_size, void* d_ws, size_t ws_size,
                              hipStream_t stream) {
  const float* q_x = (const float*)d_in[0];
  const float* k_x = (const float*)d_in[1];
  const float* v_x = (const float*)d_in[2];
  const float* energy = (const float*)d_in[3];
  const float* Wq = (const float*)d_in[4];
  const float* bq = (const float*)d_in[5];
  const float* Wk = (const float*)d_in[6];
  const float* bk = (const float*)d_in[7];
  const float* Wv = (const float*)d_in[8];
  const float* bv = (const float*)d_in[9];
  const float* Wo = (const float*)d_in[10];
  const float* bo = (const float*)d_in[11];

  char* w = (char*)d_ws;
  auto take = [&](size_t bytes) {
    char* p = w;
    w += (bytes + 255) & ~(size_t)255;
    return p;
  };
  const size_t XB = (size_t)8192 * 1024 * 2;
  unsigned short* Xq = (unsigned short*)take(XB);
  unsigned short* Xk = (unsigned short*)take(XB);
  unsigned short* Xv = (unsigned short*)take(XB);
  unsigned short* Wtq = (unsigned short*)take((size_t)1024 * 1024 * 2);
  unsigned short* Wtk = (unsigned short*)take((size_t)1024 * 1024 * 2);
  unsigned short* Wtv = (unsigned short*)take((size_t)1024 * 1024 * 2);
  unsigned short* Wto = (unsigned short*)take((size_t)1024 * 1024 * 2);
  float* mb = (float*)take((size_t)4 * 2048 * 4);
  unsigned short* Qh = (unsigned short*)take(XB);
  unsigned short* Kh = (unsigned short*)take(XB);
  unsigned short* Vt = (unsigned short*)take(XB);
  unsigned short* AO = (unsigned short*)take(XB);

  const int NX = 8192 * 1024;
  conv_bf16_kernel<<<NX / 1024, 256, 0, stream>>>(q_x, Xq, NX);
  conv_bf16_kernel<<<NX / 1024, 256, 0, stream>>>(k_x, Xk, NX);
  conv_bf16_kernel<<<NX / 1024, 256, 0, stream>>>(v_x, Xv, NX);
  wtrans_kernel<<<dim3(32, 32), dim3(32, 8), 0, stream>>>(Wq, Wtq);
  wtrans_kernel<<<dim3(32, 32), dim3(32, 8), 0, stream>>>(Wk, Wtk);
  wtrans_kernel<<<dim3(32, 32), dim3(32, 8), 0, stream>>>(Wv, Wtv);
  wtrans_kernel<<<dim3(32, 32), dim3(32, 8), 0, stream>>>(Wo, Wto);
  mask_kernel<<<32, 256, 0, stream>>>(energy, mb, 8192);

  gemm128_kernel<0><<<dim3(64, 8), 256, 0, stream>>>(Xq, Wtq, bq, (void*)Qh);
  gemm128_kernel<0><<<dim3(64, 8), 256, 0, stream>>>(Xk, Wtk, bk, (void*)Kh);
  gemm128_kernel<1><<<dim3(64, 8), 256, 0, stream>>>(Xv, Wtv, bv, (void*)Vt);
  attn_kernel<<<512, 512, 0, stream>>>(Qh, Kh, Vt, mb, AO);
  gemm128_kernel<2><<<dim3(64, 8), 256, 0, stream>>>(AO, Wto, bo, d_out);
}

// Round 7
// 269.156 us; speedup vs baseline: 1.9234x; 1.0502x over previous
//
#include <hip/hip_runtime.h>
#include <hip/hip_bf16.h>

typedef __attribute__((ext_vector_type(8))) short short8;
typedef __attribute__((ext_vector_type(4))) short short4v;
typedef __attribute__((ext_vector_type(4))) float f32x4;

static __device__ __forceinline__ unsigned short f2bf(float f) {
  unsigned int u = __float_as_uint(f);
  u += 0x7fffu + ((u >> 16) & 1u);
  return (unsigned short)(u >> 16);
}

static __device__ __forceinline__ unsigned pk2bf(float a, float b) {
  union { __hip_bfloat162 h; unsigned u; } v;
  v.h = __float22bfloat162_rn(make_float2(a, b));
  return v.u;
}

static __device__ __forceinline__ void gload_lds16(const unsigned short* g,
                                                   unsigned short* l) {
  __builtin_amdgcn_global_load_lds((const __attribute__((address_space(1))) void*)g,
                                   (__attribute__((address_space(3))) void*)l, 16, 0, 0);
}

// ---------------- converts ----------------
__global__ void conv_bf16_kernel(const float* __restrict__ in,
                                 unsigned short* __restrict__ out, int n) {
  int i = (blockIdx.x * blockDim.x + threadIdx.x) * 4;
  if (i >= n) return;
  float4 v = *(const float4*)(in + i);
  short4v o;
  o[0] = (short)f2bf(v.x); o[1] = (short)f2bf(v.y);
  o[2] = (short)f2bf(v.z); o[3] = (short)f2bf(v.w);
  *(short4v*)(out + i) = o;
}

// W [K=1024,N=1024] fp32 -> Wt [N,K] bf16
__global__ void wtrans_kernel(const float* __restrict__ W,
                              unsigned short* __restrict__ Wt) {
  __shared__ float t[32][33];
  int n0 = blockIdx.x * 32, k0 = blockIdx.y * 32;
#pragma unroll
  for (int j = 0; j < 4; ++j)
    t[threadIdx.y + j * 8][threadIdx.x] =
        W[(size_t)(k0 + threadIdx.y + j * 8) * 1024 + n0 + threadIdx.x];
  __syncthreads();
#pragma unroll
  for (int j = 0; j < 4; ++j)
    Wt[(size_t)(n0 + threadIdx.y + j * 8) * 1024 + k0 + threadIdx.x] =
        f2bf(t[threadIdx.x][threadIdx.y + j * 8]);
}

__global__ void mask_kernel(const float* __restrict__ e, float* __restrict__ mb, int n) {
  int i = blockIdx.x * blockDim.x + threadIdx.x;
  if (i < n) mb[i] = (fabsf(e[i]) > 0.1f) ? 0.0f : -1e30f;
}

// ---------------- GEMM v2: m97 pattern (global_load_lds, dbuf BK=32) ----------------
// C[M=8192,N=1024] = X @ Wt^T + bias. X bf16 [M,1024], Wt bf16 [N,K] row-major.
// LDS tiles LINEAR [128][32] bf16 (gload_lds requires contiguous lane order).
template <int MODE>
__global__ __launch_bounds__(256) void gemm128_kernel(
    const unsigned short* __restrict__ X, const unsigned short* __restrict__ Wt,
    const float* __restrict__ bias, void* __restrict__ outp) {
  const int K = 1024;
  __shared__ unsigned short Al[2][128 * 32];
  __shared__ unsigned short Bl[2][128 * 32];
  const int m0 = blockIdx.x * 128, n0 = blockIdx.y * 128;
  const int tid = threadIdx.x, lane = tid & 63, wid = tid >> 6;
  const int wr = wid >> 1, wc = wid & 1;
  const int g = lane >> 4, lr = lane & 15;
  const f32x4 fz = {0.f, 0.f, 0.f, 0.f};
  f32x4 acc[4][4];
#pragma unroll
  for (int i = 0; i < 4; i++)
#pragma unroll
    for (int j = 0; j < 4; j++) acc[i][j] = fz;

  const int sr0 = tid >> 2, sc0 = (tid & 3) * 8;
  const int sr1 = (256 + tid) >> 2;

  auto stage = [&](int kk, int buf) {
    gload_lds16(X + (size_t)(m0 + sr0) * K + kk + sc0, &Al[buf][wid * 512]);
    gload_lds16(X + (size_t)(m0 + sr1) * K + kk + sc0, &Al[buf][2048 + wid * 512]);
    gload_lds16(Wt + (size_t)(n0 + sr0) * K + kk + sc0, &Bl[buf][wid * 512]);
    gload_lds16(Wt + (size_t)(n0 + sr1) * K + kk + sc0, &Bl[buf][2048 + wid * 512]);
  };

  stage(0, 0);
  __syncthreads();

  int buf = 0;
  for (int k0 = 0; k0 < K; k0 += 32) {
    if (k0 < K - 32) stage(k0 + 32, buf ^ 1);
    short8 a[4], b[4];
#pragma unroll
    for (int i = 0; i < 4; i++)
      a[i] = *(const short8*)(&Al[buf][(wr * 64 + i * 16 + lr) * 32 + g * 8]);
#pragma unroll
    for (int i = 0; i < 4; i++)
      b[i] = *(const short8*)(&Bl[buf][(wc * 64 + i * 16 + lr) * 32 + g * 8]);
#pragma unroll
    for (int i = 0; i < 4; i++)
#pragma unroll
      for (int j = 0; j < 4; j++)
        acc[i][j] = __builtin_amdgcn_mfma_f32_16x16x32_bf16(a[i], b[j], acc[i][j], 0, 0, 0);
    __syncthreads();
    buf ^= 1;
  }

#pragma unroll
  for (int i = 0; i < 4; i++) {
    const int mrow0 = m0 + wr * 64 + i * 16 + g * 4;
#pragma unroll
    for (int j = 0; j < 4; j++) {
      const int ncol = n0 + wc * 64 + j * 16 + lr;
      const float bv = bias[ncol];
      if (MODE == 2) {
        float* out = (float*)outp;
#pragma unroll
        for (int e = 0; e < 4; e++)
          out[(size_t)(mrow0 + e) * 1024 + ncol] = acc[i][j][e] + bv;
      } else if (MODE == 0) {
        unsigned short* out = (unsigned short*)outp;
        const int h = ncol >> 6, dh = ncol & 63;
#pragma unroll
        for (int e = 0; e < 4; e++) {
          int mrow = mrow0 + e;
          int b_ = mrow >> 11, l = mrow & 2047;
          out[((size_t)(b_ * 16 + h) * 2048 + l) * 64 + dh] = f2bf(acc[i][j][e] + bv);
        }
      } else {
        unsigned short* out = (unsigned short*)outp;
        const int h = ncol >> 6, d = ncol & 63;
        const int b_ = mrow0 >> 11, s = mrow0 & 2047;
        short4v pk;
#pragma unroll
        for (int e = 0; e < 4; e++) pk[e] = (short)f2bf(acc[i][j][e] + bv);
        *(short4v*)(out + ((size_t)(b_ * 16 + h) * 64 + d) * 2048 + s) = pk;
      }
    }
  }
}

// ---------------- flash attention v7: v5 structure, phi-consistent V reads ----------
// Qh,Kh: [B,H,S,64] bf16; Vt: [B,H,64,S] bf16; mb: [B,S] fp32 bias (0/-1e30)
// AO: [B*L, 1024] bf16. Grid: 512 blocks x 512 thr (8 waves, 32 q-rows each).
// NOTE: P's C-layout gives lane (g,lr) keys {g*4..g*4+3, 16+g*4..}; the V
// (A-operand) fragment MUST use the same key permutation -> split b64 reads.
__global__ __launch_bounds__(512, 4) void attn_kernel(
    const unsigned short* __restrict__ Qh, const unsigned short* __restrict__ Kh,
    const unsigned short* __restrict__ Vt, const float* __restrict__ mb,
    unsigned short* __restrict__ AO) {
  const int S = 2048;
  __shared__ unsigned short Lds[2][8192];  // [buf][ K:0..4095 | V:4096..8191 ]
  int bx = blockIdx.x;
  int lid = (bx & 7) * 64 + (bx >> 3);
  const int bh = lid >> 3, qbb = lid & 7;
  const int b_ = bh >> 4, h = bh & 15;
  const unsigned short* Qp = Qh + (size_t)bh * S * 64;
  const unsigned short* Kp = Kh + (size_t)bh * S * 64;
  const unsigned short* Vp = Vt + (size_t)bh * 64 * S;
  const float* mbp = mb + b_ * S;
  const int tid = threadIdx.x, lane = tid & 63, wid = tid >> 6;
  const int g = lane >> 4, lr = lane & 15;
  const int qbase = qbb * 256 + wid * 32;
  const float c2 = 0.18033688011f;  // log2(e) / sqrt(64)
  const f32x4 fz = {0.f, 0.f, 0.f, 0.f};

  const int srow = (lane >> 3);
  const int schk = (lane & 7) ^ srow;
  const unsigned short* gK = Kp + (size_t)(wid * 8 + srow) * 64 + schk * 8;
  const unsigned short* gV = Vp + (size_t)(wid * 8 + srow) * S + schk * 8;

  short8 qf[2][2];
#pragma unroll
  for (int qt = 0; qt < 2; qt++)
#pragma unroll
    for (int kh = 0; kh < 2; kh++)
      qf[qt][kh] = *(const short8*)(Qp + (size_t)(qbase + qt * 16 + lr) * 64 + kh * 32 + g * 8);

  f32x4 o[2][4];
  f32x4 psum[2];
#pragma unroll
  for (int qt = 0; qt < 2; qt++) {
    psum[qt] = fz;
#pragma unroll
    for (int t = 0; t < 4; t++) o[qt][t] = fz;
  }

  gload_lds16(gK, &Lds[0][wid * 512]);
  gload_lds16(gV, &Lds[0][4096 + wid * 512]);
  __syncthreads();

  const int s7 = lr & 7;
  int cur = 0;
  for (int t = 0; t < 32; ++t) {
    const int s0 = t * 64;
    if (t < 31) {
      gload_lds16(gK + (size_t)(s0 + 64) * 64, &Lds[cur ^ 1][wid * 512]);
      gload_lds16(gV + (s0 + 64), &Lds[cur ^ 1][4096 + wid * 512]);
    }
    const unsigned short* Kb = &Lds[cur][0];
    const unsigned short* Vb = &Lds[cur][4096];

    short8 kf[4][2];
#pragma unroll
    for (int st = 0; st < 4; st++)
#pragma unroll
      for (int kh = 0; kh < 2; kh++)
        kf[st][kh] = *(const short8*)(Kb + (st * 16 + lr) * 64 + (((kh * 4 + g) ^ s7) * 8));

    f32x4 mbv[4];
#pragma unroll
    for (int st = 0; st < 4; st++)
      mbv[st] = *(const f32x4*)(mbp + s0 + st * 16 + g * 4);

    union { unsigned u[8]; short8 s8[2]; } pk[2];
#pragma unroll
    for (int qt = 0; qt < 2; qt++) {
#pragma unroll
      for (int st = 0; st < 4; st++) {
        f32x4 a0 = __builtin_amdgcn_mfma_f32_16x16x32_bf16(kf[st][0], qf[qt][0], fz, 0, 0, 0);
        f32x4 s = __builtin_amdgcn_mfma_f32_16x16x32_bf16(kf[st][1], qf[qt][1], a0, 0, 0, 0);
        f32x4 x = s * c2 + mbv[st];
        f32x4 p;
#pragma unroll
        for (int e = 0; e < 4; e++) p[e] = exp2f(x[e]);
        psum[qt] += p;
        pk[qt].u[st * 2] = pk2bf(p[0], p[1]);
        pk[qt].u[st * 2 + 1] = pk2bf(p[2], p[3]);
      }
    }

#pragma unroll
    for (int tt = 0; tt < 4; tt++) {
      const unsigned short* vb = Vb + (tt * 16 + lr) * 64;
      // phi-permuted V fragments: elem 0-3 = keys (st*16)+g*4.., elem 4-7 =
      // keys (st*16+16)+g*4.. ; chunk c read at swizzled pos (c^s7).
      union { short8 s8; short4v h[2]; } v0, v1;
      v0.h[0] = *(const short4v*)(vb + (((g >> 1) ^ s7) * 8) + (g & 1) * 4);
      v0.h[1] = *(const short4v*)(vb + (((2 + (g >> 1)) ^ s7) * 8) + (g & 1) * 4);
      v1.h[0] = *(const short4v*)(vb + (((4 + (g >> 1)) ^ s7) * 8) + (g & 1) * 4);
      v1.h[1] = *(const short4v*)(vb + (((6 + (g >> 1)) ^ s7) * 8) + (g & 1) * 4);
#pragma unroll
      for (int qt = 0; qt < 2; qt++) {
        o[qt][tt] = __builtin_amdgcn_mfma_f32_16x16x32_bf16(v0.s8, pk[qt].s8[0], o[qt][tt], 0, 0, 0);
        o[qt][tt] = __builtin_amdgcn_mfma_f32_16x16x32_bf16(v1.s8, pk[qt].s8[1], o[qt][tt], 0, 0, 0);
      }
    }
    __syncthreads();
    cur ^= 1;
  }

#pragma unroll
  for (int qt = 0; qt < 2; qt++) {
    float l = (psum[qt][0] + psum[qt][1]) + (psum[qt][2] + psum[qt][3]);
    l += __shfl_xor(l, 16);
    l += __shfl_xor(l, 32);
    float inv = l > 0.f ? 1.f / l : 0.f;
    size_t row = (size_t)b_ * 2048 + qbase + qt * 16 + lr;
#pragma unroll
    for (int tt = 0; tt < 4; tt++) {
      short4v pkv;
#pragma unroll
      for (int i = 0; i < 4; i++) pkv[i] = (short)f2bf(o[qt][tt][i] * inv);
      *(short4v*)(AO + row * 1024 + h * 64 + tt * 16 + g * 4) = pkv;
    }
  }
}

// ---------------- launch ----------------
extern "C" void kernel_launch(void* const* d_in, const int* in_sizes, int n_in,
                              void* d_out, int out_size, void* d_ws, size_t ws_size,
                              hipStream_t stream) {
  const float* q_x = (const float*)d_in[0];
  const float* k_x = (const float*)d_in[1];
  const float* v_x = (const float*)d_in[2];
  const float* energy = (const float*)d_in[3];
  const float* Wq = (const float*)d_in[4];
  const float* bq = (const float*)d_in[5];
  const float* Wk = (const float*)d_in[6];
  const float* bk = (const float*)d_in[7];
  const float* Wv = (const float*)d_in[8];
  const float* bv = (const float*)d_in[9];
  const float* Wo = (const float*)d_in[10];
  const float* bo = (const float*)d_in[11];

  char* w = (char*)d_ws;
  auto take = [&](size_t bytes) {
    char* p = w;
    w += (bytes + 255) & ~(size_t)255;
    return p;
  };
  const size_t XB = (size_t)8192 * 1024 * 2;
  unsigned short* Xq = (unsigned short*)take(XB);
  unsigned short* Xk = (unsigned short*)take(XB);
  unsigned short* Xv = (unsigned short*)take(XB);
  unsigned short* Wtq = (unsigned short*)take((size_t)1024 * 1024 * 2);
  unsigned short* Wtk = (unsigned short*)take((size_t)1024 * 1024 * 2);
  unsigned short* Wtv = (unsigned short*)take((size_t)1024 * 1024 * 2);
  unsigned short* Wto = (unsigned short*)take((size_t)1024 * 1024 * 2);
  float* mb = (float*)take((size_t)4 * 2048 * 4);
  unsigned short* Qh = (unsigned short*)take(XB);
  unsigned short* Kh = (unsigned short*)take(XB);
  unsigned short* Vt = (unsigned short*)take(XB);
  unsigned short* AO = (unsigned short*)take(XB);

  const int NX = 8192 * 1024;
  conv_bf16_kernel<<<NX / 1024, 256, 0, stream>>>(q_x, Xq, NX);
  conv_bf16_kernel<<<NX / 1024, 256, 0, stream>>>(k_x, Xk, NX);
  conv_bf16_kernel<<<NX / 1024, 256, 0, stream>>>(v_x, Xv, NX);
  wtrans_kernel<<<dim3(32, 32), dim3(32, 8), 0, stream>>>(Wq, Wtq);
  wtrans_kernel<<<dim3(32, 32), dim3(32, 8), 0, stream>>>(Wk, Wtk);
  wtrans_kernel<<<dim3(32, 32), dim3(32, 8), 0, stream>>>(Wv, Wtv);
  wtrans_kernel<<<dim3(32, 32), dim3(32, 8), 0, stream>>>(Wo, Wto);
  mask_kernel<<<32, 256, 0, stream>>>(energy, mb, 8192);

  gemm128_kernel<0><<<dim3(64, 8), 256, 0, stream>>>(Xq, Wtq, bq, (void*)Qh);
  gemm128_kernel<0><<<dim3(64, 8), 256, 0, stream>>>(Xk, Wtk, bk, (void*)Kh);
  gemm128_kernel<1><<<dim3(64, 8), 256, 0, stream>>>(Xv, Wtv, bv, (void*)Vt);
  attn_kernel<<<512, 512, 0, stream>>>(Qh, Kh, Vt, mb, AO);
  gemm128_kernel<2><<<dim3(64, 8), 256, 0, stream>>>(AO, Wto, bo, d_out);
}

// Round 8
// 267.640 us; speedup vs baseline: 1.9343x; 1.0057x over previous
//
#include <hip/hip_runtime.h>
#include <hip/hip_bf16.h>

typedef __attribute__((ext_vector_type(8))) short short8;
typedef __attribute__((ext_vector_type(4))) short short4v;
typedef __attribute__((ext_vector_type(4))) float f32x4;

static __device__ __forceinline__ unsigned short f2bf(float f) {
  unsigned int u = __float_as_uint(f);
  u += 0x7fffu + ((u >> 16) & 1u);
  return (unsigned short)(u >> 16);
}

static __device__ __forceinline__ unsigned pk2bf(float a, float b) {
  union { __hip_bfloat162 h; unsigned u; } v;
  v.h = __float22bfloat162_rn(make_float2(a, b));
  return v.u;
}

static __device__ __forceinline__ void gload_lds16(const unsigned short* g,
                                                   unsigned short* l) {
  __builtin_amdgcn_global_load_lds((const __attribute__((address_space(1))) void*)g,
                                   (__attribute__((address_space(3))) void*)l, 16, 0, 0);
}

// ---------------- converts ----------------
__global__ void conv_bf16_kernel(const float* __restrict__ in,
                                 unsigned short* __restrict__ out, int n) {
  int i = (blockIdx.x * blockDim.x + threadIdx.x) * 4;
  if (i >= n) return;
  float4 v = *(const float4*)(in + i);
  short4v o;
  o[0] = (short)f2bf(v.x); o[1] = (short)f2bf(v.y);
  o[2] = (short)f2bf(v.z); o[3] = (short)f2bf(v.w);
  *(short4v*)(out + i) = o;
}

// W [K=1024,N=1024] fp32 -> Wt [N,K] bf16
__global__ void wtrans_kernel(const float* __restrict__ W,
                              unsigned short* __restrict__ Wt) {
  __shared__ float t[32][33];
  int n0 = blockIdx.x * 32, k0 = blockIdx.y * 32;
#pragma unroll
  for (int j = 0; j < 4; ++j)
    t[threadIdx.y + j * 8][threadIdx.x] =
        W[(size_t)(k0 + threadIdx.y + j * 8) * 1024 + n0 + threadIdx.x];
  __syncthreads();
#pragma unroll
  for (int j = 0; j < 4; ++j)
    Wt[(size_t)(n0 + threadIdx.y + j * 8) * 1024 + k0 + threadIdx.x] =
        f2bf(t[threadIdx.x][threadIdx.y + j * 8]);
}

__global__ void mask_kernel(const float* __restrict__ e, float* __restrict__ mb, int n) {
  int i = blockIdx.x * blockDim.x + threadIdx.x;
  if (i < n) mb[i] = (fabsf(e[i]) > 0.1f) ? 0.0f : -1e30f;
}

// ---------------- GEMM v2: m97 pattern (global_load_lds, dbuf BK=32) ----------------
template <int MODE>
__global__ __launch_bounds__(256) void gemm128_kernel(
    const unsigned short* __restrict__ X, const unsigned short* __restrict__ Wt,
    const float* __restrict__ bias, void* __restrict__ outp) {
  const int K = 1024;
  __shared__ unsigned short Al[2][128 * 32];
  __shared__ unsigned short Bl[2][128 * 32];
  const int m0 = blockIdx.x * 128, n0 = blockIdx.y * 128;
  const int tid = threadIdx.x, lane = tid & 63, wid = tid >> 6;
  const int wr = wid >> 1, wc = wid & 1;
  const int g = lane >> 4, lr = lane & 15;
  const f32x4 fz = {0.f, 0.f, 0.f, 0.f};
  f32x4 acc[4][4];
#pragma unroll
  for (int i = 0; i < 4; i++)
#pragma unroll
    for (int j = 0; j < 4; j++) acc[i][j] = fz;

  const int sr0 = tid >> 2, sc0 = (tid & 3) * 8;
  const int sr1 = (256 + tid) >> 2;

  auto stage = [&](int kk, int buf) {
    gload_lds16(X + (size_t)(m0 + sr0) * K + kk + sc0, &Al[buf][wid * 512]);
    gload_lds16(X + (size_t)(m0 + sr1) * K + kk + sc0, &Al[buf][2048 + wid * 512]);
    gload_lds16(Wt + (size_t)(n0 + sr0) * K + kk + sc0, &Bl[buf][wid * 512]);
    gload_lds16(Wt + (size_t)(n0 + sr1) * K + kk + sc0, &Bl[buf][2048 + wid * 512]);
  };

  stage(0, 0);
  __syncthreads();

  int buf = 0;
  for (int k0 = 0; k0 < K; k0 += 32) {
    if (k0 < K - 32) stage(k0 + 32, buf ^ 1);
    short8 a[4], b[4];
#pragma unroll
    for (int i = 0; i < 4; i++)
      a[i] = *(const short8*)(&Al[buf][(wr * 64 + i * 16 + lr) * 32 + g * 8]);
#pragma unroll
    for (int i = 0; i < 4; i++)
      b[i] = *(const short8*)(&Bl[buf][(wc * 64 + i * 16 + lr) * 32 + g * 8]);
#pragma unroll
    for (int i = 0; i < 4; i++)
#pragma unroll
      for (int j = 0; j < 4; j++)
        acc[i][j] = __builtin_amdgcn_mfma_f32_16x16x32_bf16(a[i], b[j], acc[i][j], 0, 0, 0);
    __syncthreads();
    buf ^= 1;
  }

#pragma unroll
  for (int i = 0; i < 4; i++) {
    const int mrow0 = m0 + wr * 64 + i * 16 + g * 4;
#pragma unroll
    for (int j = 0; j < 4; j++) {
      const int ncol = n0 + wc * 64 + j * 16 + lr;
      const float bv = bias[ncol];
      if (MODE == 2) {
        float* out = (float*)outp;
#pragma unroll
        for (int e = 0; e < 4; e++)
          out[(size_t)(mrow0 + e) * 1024 + ncol] = acc[i][j][e] + bv;
      } else if (MODE == 0) {
        unsigned short* out = (unsigned short*)outp;
        const int h = ncol >> 6, dh = ncol & 63;
#pragma unroll
        for (int e = 0; e < 4; e++) {
          int mrow = mrow0 + e;
          int b_ = mrow >> 11, l = mrow & 2047;
          out[((size_t)(b_ * 16 + h) * 2048 + l) * 64 + dh] = f2bf(acc[i][j][e] + bv);
        }
      } else {
        unsigned short* out = (unsigned short*)outp;
        const int h = ncol >> 6, d = ncol & 63;
        const int b_ = mrow0 >> 11, s = mrow0 & 2047;
        short4v pk;
#pragma unroll
        for (int e = 0; e < 4; e++) pk[e] = (short)f2bf(acc[i][j][e] + bv);
        *(short4v*)(out + ((size_t)(b_ * 16 + h) * 64 + d) * 2048 + s) = pk;
      }
    }
  }
}

// ---------------- flash attention v8: pi-permuted K staging ----------------
// Qh,Kh: [B,H,S,64] bf16; Vt: [B,H,64,S] bf16; mb: [B,S] fp32 bias (0/-1e30)
// AO: [B*L, 1024] bf16. Grid: 512 blocks x 512 thr (8 waves, 32 q-rows each).
// K rows staged in pi-permuted order, pi(p)=(p&32)|((p&12)<<1)|((p&16)>>2)|(p&3),
// so P's C-layout per lane covers 8 CONTIGUOUS global keys -> V fragment is one
// ds_read_b128 per 32-key half with per-thread-constant swizzled offset.
// Mask bias is read pi-consistently; softmax-sum is permutation-invariant.
__global__ __launch_bounds__(512, 4) void attn_kernel(
    const unsigned short* __restrict__ Qh, const unsigned short* __restrict__ Kh,
    const unsigned short* __restrict__ Vt, const float* __restrict__ mb,
    unsigned short* __restrict__ AO) {
  const int S = 2048;
  __shared__ unsigned short Lds[2][8192];  // [buf][ K:0..4095 | V:4096..8191 ]
  int bx = blockIdx.x;
  int lid = (bx & 7) * 64 + (bx >> 3);
  const int bh = lid >> 3, qbb = lid & 7;
  const int b_ = bh >> 4, h = bh & 15;
  const unsigned short* Qp = Qh + (size_t)bh * S * 64;
  const unsigned short* Kp = Kh + (size_t)bh * S * 64;
  const unsigned short* Vp = Vt + (size_t)bh * 64 * S;
  const float* mbp = mb + b_ * S;
  const int tid = threadIdx.x, lane = tid & 63, wid = tid >> 6;
  const int g = lane >> 4, lr = lane & 15;
  const int qbase = qbb * 256 + wid * 32;
  const float c2 = 0.18033688011f;  // log2(e) / sqrt(64)
  const f32x4 fz = {0.f, 0.f, 0.f, 0.f};

  // staging geometry: wave stages 8 rows x 128B of K and of V; chunk swizzle
  // (^srow) on the SOURCE so swizzled ds_reads see the natural layout.
  const int srow = (lane >> 3);
  const int schk = (lane & 7) ^ srow;
  const int krow = wid * 8 + srow;  // LDS K row
  const int pir = (krow & 32) | ((krow & 12) << 1) | ((krow & 16) >> 2) | (krow & 3);
  const unsigned short* gK = Kp + (size_t)pir * 64 + schk * 8;
  const unsigned short* gV = Vp + (size_t)krow * S + schk * 8;

  // per-thread-constant swizzled chunk offsets (shorts) for K and V reads
  const int s7 = lr & 7;
  const int off0 = ((g ^ s7) * 8);
  const int off1 = (((4 + g) ^ s7) * 8);

  short8 qf[2][2];
#pragma unroll
  for (int qt = 0; qt < 2; qt++)
#pragma unroll
    for (int kh = 0; kh < 2; kh++)
      qf[qt][kh] = *(const short8*)(Qp + (size_t)(qbase + qt * 16 + lr) * 64 + kh * 32 + g * 8);

  f32x4 o[2][4];
  f32x4 psum[2];
#pragma unroll
  for (int qt = 0; qt < 2; qt++) {
    psum[qt] = fz;
#pragma unroll
    for (int t = 0; t < 4; t++) o[qt][t] = fz;
  }

  gload_lds16(gK, &Lds[0][wid * 512]);
  gload_lds16(gV, &Lds[0][4096 + wid * 512]);
  __syncthreads();

  int cur = 0;
  for (int t = 0; t < 32; ++t) {
    const int s0 = t * 64;
    if (t < 31) {
      gload_lds16(gK + (size_t)(s0 + 64) * 64, &Lds[cur ^ 1][wid * 512]);
      gload_lds16(gV + (s0 + 64), &Lds[cur ^ 1][4096 + wid * 512]);
    }
    const unsigned short* Kb = &Lds[cur][lr * 64];
    const unsigned short* Vb = &Lds[cur][4096 + lr * 64];

    short8 kf[4][2];
#pragma unroll
    for (int st = 0; st < 4; st++) {
      kf[st][0] = *(const short8*)(Kb + st * 1024 + off0);
      kf[st][1] = *(const short8*)(Kb + st * 1024 + off1);
    }

    // pi-consistent mask bias: element (st,g,e) is key (st>>1)*32 + g*8 + (st&1)*4 + e
    f32x4 mbv[4];
#pragma unroll
    for (int st = 0; st < 4; st++)
      mbv[st] = *(const f32x4*)(mbp + s0 + (st >> 1) * 32 + (st & 1) * 4 + g * 8);

    union { unsigned u[8]; short8 s8[2]; } pk[2];
    __builtin_amdgcn_s_setprio(1);
#pragma unroll
    for (int qt = 0; qt < 2; qt++) {
#pragma unroll
      for (int st = 0; st < 4; st++) {
        f32x4 a0 = __builtin_amdgcn_mfma_f32_16x16x32_bf16(kf[st][0], qf[qt][0], fz, 0, 0, 0);
        f32x4 s = __builtin_amdgcn_mfma_f32_16x16x32_bf16(kf[st][1], qf[qt][1], a0, 0, 0, 0);
        f32x4 x = s * c2 + mbv[st];
        f32x4 p;
#pragma unroll
        for (int e = 0; e < 4; e++) p[e] = exp2f(x[e]);
        psum[qt] += p;
        pk[qt].u[st * 2] = pk2bf(p[0], p[1]);
        pk[qt].u[st * 2 + 1] = pk2bf(p[2], p[3]);
      }
    }
    __builtin_amdgcn_s_setprio(0);

#pragma unroll
    for (int tt = 0; tt < 4; tt++) {
      // keys for this lane are contiguous: v0 = keys g*8..g*8+7 (half 0),
      // v1 = keys 32+g*8.. (half 1); chunk c stored at position c^s7.
      short8 v0 = *(const short8*)(Vb + tt * 1024 + off0);
      short8 v1 = *(const short8*)(Vb + tt * 1024 + off1);
      __builtin_amdgcn_s_setprio(1);
#pragma unroll
      for (int qt = 0; qt < 2; qt++) {
        o[qt][tt] = __builtin_amdgcn_mfma_f32_16x16x32_bf16(v0, pk[qt].s8[0], o[qt][tt], 0, 0, 0);
        o[qt][tt] = __builtin_amdgcn_mfma_f32_16x16x32_bf16(v1, pk[qt].s8[1], o[qt][tt], 0, 0, 0);
      }
      __builtin_amdgcn_s_setprio(0);
    }
    __syncthreads();
    cur ^= 1;
  }

#pragma unroll
  for (int qt = 0; qt < 2; qt++) {
    float l = (psum[qt][0] + psum[qt][1]) + (psum[qt][2] + psum[qt][3]);
    l += __shfl_xor(l, 16);
    l += __shfl_xor(l, 32);
    float inv = l > 0.f ? 1.f / l : 0.f;
    size_t row = (size_t)b_ * 2048 + qbase + qt * 16 + lr;
#pragma unroll
    for (int tt = 0; tt < 4; tt++) {
      short4v pkv;
#pragma unroll
      for (int i = 0; i < 4; i++) pkv[i] = (short)f2bf(o[qt][tt][i] * inv);
      *(short4v*)(AO + row * 1024 + h * 64 + tt * 16 + g * 4) = pkv;
    }
  }
}

// ---------------- launch ----------------
extern "C" void kernel_launch(void* const* d_in, const int* in_sizes, int n_in,
                              void* d_out, int out_size, void* d_ws, size_t ws_size,
                              hipStream_t stream) {
  const float* q_x = (const float*)d_in[0];
  const float* k_x = (const float*)d_in[1];
  const float* v_x = (const float*)d_in[2];
  const float* energy = (const float*)d_in[3];
  const float* Wq = (const float*)d_in[4];
  const float* bq = (const float*)d_in[5];
  const float* Wk = (const float*)d_in[6];
  const float* bk = (const float*)d_in[7];
  const float* Wv = (const float*)d_in[8];
  const float* bv = (const float*)d_in[9];
  const float* Wo = (const float*)d_in[10];
  const float* bo = (const float*)d_in[11];

  char* w = (char*)d_ws;
  auto take = [&](size_t bytes) {
    char* p = w;
    w += (bytes + 255) & ~(size_t)255;
    return p;
  };
  const size_t XB = (size_t)8192 * 1024 * 2;
  unsigned short* Xq = (unsigned short*)take(XB);
  unsigned short* Xk = (unsigned short*)take(XB);
  unsigned short* Xv = (unsigned short*)take(XB);
  unsigned short* Wtq = (unsigned short*)take((size_t)1024 * 1024 * 2);
  unsigned short* Wtk = (unsigned short*)take((size_t)1024 * 1024 * 2);
  unsigned short* Wtv = (unsigned short*)take((size_t)1024 * 1024 * 2);
  unsigned short* Wto = (unsigned short*)take((size_t)1024 * 1024 * 2);
  float* mb = (float*)take((size_t)4 * 2048 * 4);
  unsigned short* Qh = (unsigned short*)take(XB);
  unsigned short* Kh = (unsigned short*)take(XB);
  unsigned short* Vt = (unsigned short*)take(XB);
  unsigned short* AO = (unsigned short*)take(XB);

  const int NX = 8192 * 1024;
  conv_bf16_kernel<<<NX / 1024, 256, 0, stream>>>(q_x, Xq, NX);
  conv_bf16_kernel<<<NX / 1024, 256, 0, stream>>>(k_x, Xk, NX);
  conv_bf16_kernel<<<NX / 1024, 256, 0, stream>>>(v_x, Xv, NX);
  wtrans_kernel<<<dim3(32, 32), dim3(32, 8), 0, stream>>>(Wq, Wtq);
  wtrans_kernel<<<dim3(32, 32), dim3(32, 8), 0, stream>>>(Wk, Wtk);
  wtrans_kernel<<<dim3(32, 32), dim3(32, 8), 0, stream>>>(Wv, Wtv);
  wtrans_kernel<<<dim3(32, 32), dim3(32, 8), 0, stream>>>(Wo, Wto);
  mask_kernel<<<32, 256, 0, stream>>>(energy, mb, 8192);

  gemm128_kernel<0><<<dim3(64, 8), 256, 0, stream>>>(Xq, Wtq, bq, (void*)Qh);
  gemm128_kernel<0><<<dim3(64, 8), 256, 0, stream>>>(Xk, Wtk, bk, (void*)Kh);
  gemm128_kernel<1><<<dim3(64, 8), 256, 0, stream>>>(Xv, Wtv, bv, (void*)Vt);
  attn_kernel<<<512, 512, 0, stream>>>(Qh, Kh, Vt, mb, AO);
  gemm128_kernel<2><<<dim3(64, 8), 256, 0, stream>>>(AO, Wto, bo, d_out);
}

// Round 9
// 265.210 us; speedup vs baseline: 1.9520x; 1.0092x over previous
//
#include <hip/hip_runtime.h>
#include <hip/hip_bf16.h>

typedef __attribute__((ext_vector_type(8))) short short8;
typedef __attribute__((ext_vector_type(4))) short short4v;
typedef __attribute__((ext_vector_type(4))) float f32x4;

static __device__ __forceinline__ unsigned short f2bf(float f) {
  unsigned int u = __float_as_uint(f);
  u += 0x7fffu + ((u >> 16) & 1u);
  return (unsigned short)(u >> 16);
}

static __device__ __forceinline__ unsigned pk2bf(float a, float b) {
  union { __hip_bfloat162 h; unsigned u; } v;
  v.h = __float22bfloat162_rn(make_float2(a, b));
  return v.u;
}

static __device__ __forceinline__ void gload_lds16(const unsigned short* g,
                                                   unsigned short* l) {
  __builtin_amdgcn_global_load_lds((const __attribute__((address_space(1))) void*)g,
                                   (__attribute__((address_space(3))) void*)l, 16, 0, 0);
}

// ---------------- converts ----------------
__global__ void conv_bf16_kernel(const float* __restrict__ in,
                                 unsigned short* __restrict__ out, int n) {
  int i = (blockIdx.x * blockDim.x + threadIdx.x) * 4;
  if (i >= n) return;
  float4 v = *(const float4*)(in + i);
  short4v o;
  o[0] = (short)f2bf(v.x); o[1] = (short)f2bf(v.y);
  o[2] = (short)f2bf(v.z); o[3] = (short)f2bf(v.w);
  *(short4v*)(out + i) = o;
}

// W [K=1024,N=1024] fp32 -> Wt [N,K] bf16
__global__ void wtrans_kernel(const float* __restrict__ W,
                              unsigned short* __restrict__ Wt) {
  __shared__ float t[32][33];
  int n0 = blockIdx.x * 32, k0 = blockIdx.y * 32;
#pragma unroll
  for (int j = 0; j < 4; ++j)
    t[threadIdx.y + j * 8][threadIdx.x] =
        W[(size_t)(k0 + threadIdx.y + j * 8) * 1024 + n0 + threadIdx.x];
  __syncthreads();
#pragma unroll
  for (int j = 0; j < 4; ++j)
    Wt[(size_t)(n0 + threadIdx.y + j * 8) * 1024 + k0 + threadIdx.x] =
        f2bf(t[threadIdx.x][threadIdx.y + j * 8]);
}

__global__ void mask_kernel(const float* __restrict__ e, float* __restrict__ mb, int n) {
  int i = blockIdx.x * blockDim.x + threadIdx.x;
  if (i < n) mb[i] = (fabsf(e[i]) > 0.1f) ? 0.0f : -1e30f;
}

// ---------------- GEMM v2: m97 pattern (global_load_lds, dbuf BK=32) ----------------
template <int MODE>
__global__ __launch_bounds__(256) void gemm128_kernel(
    const unsigned short* __restrict__ X, const unsigned short* __restrict__ Wt,
    const float* __restrict__ bias, void* __restrict__ outp) {
  const int K = 1024;
  __shared__ unsigned short Al[2][128 * 32];
  __shared__ unsigned short Bl[2][128 * 32];
  const int m0 = blockIdx.x * 128, n0 = blockIdx.y * 128;
  const int tid = threadIdx.x, lane = tid & 63, wid = tid >> 6;
  const int wr = wid >> 1, wc = wid & 1;
  const int g = lane >> 4, lr = lane & 15;
  const f32x4 fz = {0.f, 0.f, 0.f, 0.f};
  f32x4 acc[4][4];
#pragma unroll
  for (int i = 0; i < 4; i++)
#pragma unroll
    for (int j = 0; j < 4; j++) acc[i][j] = fz;

  const int sr0 = tid >> 2, sc0 = (tid & 3) * 8;
  const int sr1 = (256 + tid) >> 2;

  auto stage = [&](int kk, int buf) {
    gload_lds16(X + (size_t)(m0 + sr0) * K + kk + sc0, &Al[buf][wid * 512]);
    gload_lds16(X + (size_t)(m0 + sr1) * K + kk + sc0, &Al[buf][2048 + wid * 512]);
    gload_lds16(Wt + (size_t)(n0 + sr0) * K + kk + sc0, &Bl[buf][wid * 512]);
    gload_lds16(Wt + (size_t)(n0 + sr1) * K + kk + sc0, &Bl[buf][2048 + wid * 512]);
  };

  stage(0, 0);
  __syncthreads();

  int buf = 0;
  for (int k0 = 0; k0 < K; k0 += 32) {
    if (k0 < K - 32) stage(k0 + 32, buf ^ 1);
    short8 a[4], b[4];
#pragma unroll
    for (int i = 0; i < 4; i++)
      a[i] = *(const short8*)(&Al[buf][(wr * 64 + i * 16 + lr) * 32 + g * 8]);
#pragma unroll
    for (int i = 0; i < 4; i++)
      b[i] = *(const short8*)(&Bl[buf][(wc * 64 + i * 16 + lr) * 32 + g * 8]);
#pragma unroll
    for (int i = 0; i < 4; i++)
#pragma unroll
      for (int j = 0; j < 4; j++)
        acc[i][j] = __builtin_amdgcn_mfma_f32_16x16x32_bf16(a[i], b[j], acc[i][j], 0, 0, 0);
    __syncthreads();
    buf ^= 1;
  }

#pragma unroll
  for (int i = 0; i < 4; i++) {
    const int mrow0 = m0 + wr * 64 + i * 16 + g * 4;
#pragma unroll
    for (int j = 0; j < 4; j++) {
      const int ncol = n0 + wc * 64 + j * 16 + lr;
      const float bv = bias[ncol];
      if (MODE == 2) {
        float* out = (float*)outp;
#pragma unroll
        for (int e = 0; e < 4; e++)
          out[(size_t)(mrow0 + e) * 1024 + ncol] = acc[i][j][e] + bv;
      } else if (MODE == 0) {
        unsigned short* out = (unsigned short*)outp;
        const int h = ncol >> 6, dh = ncol & 63;
#pragma unroll
        for (int e = 0; e < 4; e++) {
          int mrow = mrow0 + e;
          int b_ = mrow >> 11, l = mrow & 2047;
          out[((size_t)(b_ * 16 + h) * 2048 + l) * 64 + dh] = f2bf(acc[i][j][e] + bv);
        }
      } else {
        unsigned short* out = (unsigned short*)outp;
        const int h = ncol >> 6, d = ncol & 63;
        const int b_ = mrow0 >> 11, s = mrow0 & 2047;
        short4v pk;
#pragma unroll
        for (int e = 0; e < 4; e++) pk[e] = (short)f2bf(acc[i][j][e] + bv);
        *(short4v*)(out + ((size_t)(b_ * 16 + h) * 64 + d) * 2048 + s) = pk;
      }
    }
  }
}

// ---------------- flash attention v9: v8 + real VGPR budget + ones-MFMA psum -------
// Qh,Kh: [B,H,S,64] bf16; Vt: [B,H,64,S] bf16; mb: [B,S] fp32 bias (0/-1e30)
// AO: [B*L, 1024] bf16. Grid: 1024 blocks x 256 thr (4 waves, 32 q-rows each).
// waves_per_eu(2,3): ~170-VGPR budget so kf/o/qf stay register-resident
// (launch_bounds(512,4) made the compiler shrink to 64 VGPRs -> remat storm).
// Softmax denominator accumulated by mfma(ones, pk) on the idle matrix pipe.
__global__ __launch_bounds__(256) __attribute__((amdgpu_waves_per_eu(2, 3)))
void attn_kernel(
    const unsigned short* __restrict__ Qh, const unsigned short* __restrict__ Kh,
    const unsigned short* __restrict__ Vt, const float* __restrict__ mb,
    unsigned short* __restrict__ AO) {
  const int S = 2048;
  __shared__ unsigned short Lds[2][8192];  // [buf][ K:0..4095 | V:4096..8191 ]
  int bx = blockIdx.x;
  int lid = (bx & 7) * 128 + (bx >> 3);   // 8 XCDs x 128; 16 q-blocks per bh
  const int bh = lid >> 4, qbb = lid & 15;
  const int b_ = bh >> 4, h = bh & 15;
  const unsigned short* Qp = Qh + (size_t)bh * S * 64;
  const unsigned short* Kp = Kh + (size_t)bh * S * 64;
  const unsigned short* Vp = Vt + (size_t)bh * 64 * S;
  const float* mbp = mb + b_ * S;
  const int tid = threadIdx.x, lane = tid & 63, wid = tid >> 6;
  const int g = lane >> 4, lr = lane & 15;
  const int qbase = qbb * 128 + wid * 32;
  const float c2 = 0.18033688011f;  // log2(e) / sqrt(64)
  const f32x4 fz = {0.f, 0.f, 0.f, 0.f};

  // staging: wave covers rows wid*16 + c*8 + srow (c=0,1) of K and V tiles.
  const int srow = (lane >> 3);
  const int schk = (lane & 7) ^ srow;
  const int kr0 = wid * 16 + srow, kr1 = wid * 16 + 8 + srow;
  const int pir0 = (kr0 & 32) | ((kr0 & 12) << 1) | ((kr0 & 16) >> 2) | (kr0 & 3);
  const int pir1 = (kr1 & 32) | ((kr1 & 12) << 1) | ((kr1 & 16) >> 2) | (kr1 & 3);
  const unsigned short* gK0 = Kp + (size_t)pir0 * 64 + schk * 8;
  const unsigned short* gK1 = Kp + (size_t)pir1 * 64 + schk * 8;
  const unsigned short* gV0 = Vp + (size_t)kr0 * S + schk * 8;
  const unsigned short* gV1 = Vp + (size_t)kr1 * S + schk * 8;

  const int s7 = lr & 7;
  const int off0 = ((g ^ s7) * 8);
  const int off1 = (((4 + g) ^ s7) * 8);

  short8 qf[2][2];
#pragma unroll
  for (int qt = 0; qt < 2; qt++)
#pragma unroll
    for (int kh = 0; kh < 2; kh++)
      qf[qt][kh] = *(const short8*)(Qp + (size_t)(qbase + qt * 16 + lr) * 64 + kh * 32 + g * 8);

  short8 ones;
#pragma unroll
  for (int i = 0; i < 8; i++) ones[i] = (short)0x3F80;  // bf16 1.0

  f32x4 o[2][4];
  f32x4 psA[2];
#pragma unroll
  for (int qt = 0; qt < 2; qt++) {
    psA[qt] = fz;
#pragma unroll
    for (int t = 0; t < 4; t++) o[qt][t] = fz;
  }

  auto stage = [&](int s0, int buf) {
    gload_lds16(gK0 + (size_t)s0 * 64, &Lds[buf][wid * 1024]);
    gload_lds16(gK1 + (size_t)s0 * 64, &Lds[buf][wid * 1024 + 512]);
    gload_lds16(gV0 + s0, &Lds[buf][4096 + wid * 1024]);
    gload_lds16(gV1 + s0, &Lds[buf][4096 + wid * 1024 + 512]);
  };

  stage(0, 0);
  __syncthreads();

  int cur = 0;
  for (int t = 0; t < 32; ++t) {
    const int s0 = t * 64;
    if (t < 31) stage(s0 + 64, cur ^ 1);
    const unsigned short* Kb = &Lds[cur][lr * 64];
    const unsigned short* Vb = &Lds[cur][4096 + lr * 64];

    short8 kf[4][2];
#pragma unroll
    for (int st = 0; st < 4; st++) {
      kf[st][0] = *(const short8*)(Kb + st * 1024 + off0);
      kf[st][1] = *(const short8*)(Kb + st * 1024 + off1);
    }

    f32x4 mbv[4];
#pragma unroll
    for (int st = 0; st < 4; st++)
      mbv[st] = *(const f32x4*)(mbp + s0 + (st >> 1) * 32 + (st & 1) * 4 + g * 8);

    union { unsigned u[8]; short8 s8[2]; } pk[2];
    __builtin_amdgcn_s_setprio(1);
#pragma unroll
    for (int qt = 0; qt < 2; qt++) {
#pragma unroll
      for (int st = 0; st < 4; st++) {
        f32x4 a0 = __builtin_amdgcn_mfma_f32_16x16x32_bf16(kf[st][0], qf[qt][0], fz, 0, 0, 0);
        f32x4 s = __builtin_amdgcn_mfma_f32_16x16x32_bf16(kf[st][1], qf[qt][1], a0, 0, 0, 0);
        f32x4 x = s * c2 + mbv[st];
        f32x4 p;
#pragma unroll
        for (int e = 0; e < 4; e++) p[e] = exp2f(x[e]);
        pk[qt].u[st * 2] = pk2bf(p[0], p[1]);
        pk[qt].u[st * 2 + 1] = pk2bf(p[2], p[3]);
      }
      // denominator on the matrix pipe: ones-row sums all 32 keys per half
      psA[qt] = __builtin_amdgcn_mfma_f32_16x16x32_bf16(ones, pk[qt].s8[0], psA[qt], 0, 0, 0);
      psA[qt] = __builtin_amdgcn_mfma_f32_16x16x32_bf16(ones, pk[qt].s8[1], psA[qt], 0, 0, 0);
    }
    __builtin_amdgcn_s_setprio(0);

#pragma unroll
    for (int tt = 0; tt < 4; tt++) {
      short8 v0 = *(const short8*)(Vb + tt * 1024 + off0);
      short8 v1 = *(const short8*)(Vb + tt * 1024 + off1);
      __builtin_amdgcn_s_setprio(1);
#pragma unroll
      for (int qt = 0; qt < 2; qt++) {
        o[qt][tt] = __builtin_amdgcn_mfma_f32_16x16x32_bf16(v0, pk[qt].s8[0], o[qt][tt], 0, 0, 0);
        o[qt][tt] = __builtin_amdgcn_mfma_f32_16x16x32_bf16(v1, pk[qt].s8[1], o[qt][tt], 0, 0, 0);
      }
      __builtin_amdgcn_s_setprio(0);
    }
    __syncthreads();
    cur ^= 1;
  }

#pragma unroll
  for (int qt = 0; qt < 2; qt++) {
    float l = psA[qt][0];  // all rows/groups identical by construction
    float inv = l > 0.f ? 1.f / l : 0.f;
    size_t row = (size_t)b_ * 2048 + qbase + qt * 16 + lr;
#pragma unroll
    for (int tt = 0; tt < 4; tt++) {
      short4v pkv;
#pragma unroll
      for (int i = 0; i < 4; i++) pkv[i] = (short)f2bf(o[qt][tt][i] * inv);
      *(short4v*)(AO + row * 1024 + h * 64 + tt * 16 + g * 4) = pkv;
    }
  }
}

// ---------------- launch ----------------
extern "C" void kernel_launch(void* const* d_in, const int* in_sizes, int n_in,
                              void* d_out, int out_size, void* d_ws, size_t ws_size,
                              hipStream_t stream) {
  const float* q_x = (const float*)d_in[0];
  const float* k_x = (const float*)d_in[1];
  const float* v_x = (const float*)d_in[2];
  const float* energy = (const float*)d_in[3];
  const float* Wq = (const float*)d_in[4];
  const float* bq = (const float*)d_in[5];
  const float* Wk = (const float*)d_in[6];
  const float* bk = (const float*)d_in[7];
  const float* Wv = (const float*)d_in[8];
  const float* bv = (const float*)d_in[9];
  const float* Wo = (const float*)d_in[10];
  const float* bo = (const float*)d_in[11];

  char* w = (char*)d_ws;
  auto take = [&](size_t bytes) {
    char* p = w;
    w += (bytes + 255) & ~(size_t)255;
    return p;
  };
  const size_t XB = (size_t)8192 * 1024 * 2;
  unsigned short* Xq = (unsigned short*)take(XB);
  unsigned short* Xk = (unsigned short*)take(XB);
  unsigned short* Xv = (unsigned short*)take(XB);
  unsigned short* Wtq = (unsigned short*)take((size_t)1024 * 1024 * 2);
  unsigned short* Wtk = (unsigned short*)take((size_t)1024 * 1024 * 2);
  unsigned short* Wtv = (unsigned short*)take((size_t)1024 * 1024 * 2);
  unsigned short* Wto = (unsigned short*)take((size_t)1024 * 1024 * 2);
  float* mb = (float*)take((size_t)4 * 2048 * 4);
  unsigned short* Qh = (unsigned short*)take(XB);
  unsigned short* Kh = (unsigned short*)take(XB);
  unsigned short* Vt = (unsigned short*)take(XB);
  unsigned short* AO = (unsigned short*)take(XB);

  const int NX = 8192 * 1024;
  conv_bf16_kernel<<<NX / 1024, 256, 0, stream>>>(q_x, Xq, NX);
  conv_bf16_kernel<<<NX / 1024, 256, 0, stream>>>(k_x, Xk, NX);
  conv_bf16_kernel<<<NX / 1024, 256, 0, stream>>>(v_x, Xv, NX);
  wtrans_kernel<<<dim3(32, 32), dim3(32, 8), 0, stream>>>(Wq, Wtq);
  wtrans_kernel<<<dim3(32, 32), dim3(32, 8), 0, stream>>>(Wk, Wtk);
  wtrans_kernel<<<dim3(32, 32), dim3(32, 8), 0, stream>>>(Wv, Wtv);
  wtrans_kernel<<<dim3(32, 32), dim3(32, 8), 0, stream>>>(Wo, Wto);
  mask_kernel<<<32, 256, 0, stream>>>(energy, mb, 8192);

  gemm128_kernel<0><<<dim3(64, 8), 256, 0, stream>>>(Xq, Wtq, bq, (void*)Qh);
  gemm128_kernel<0><<<dim3(64, 8), 256, 0, stream>>>(Xk, Wtk, bk, (void*)Kh);
  gemm128_kernel<1><<<dim3(64, 8), 256, 0, stream>>>(Xv, Wtv, bv, (void*)Vt);
  attn_kernel<<<1024, 256, 0, stream>>>(Qh, Kh, Vt, mb, AO);
  gemm128_kernel<2><<<dim3(64, 8), 256, 0, stream>>>(AO, Wto, bo, d_out);
}

// Round 10
// 222.913 us; speedup vs baseline: 2.3224x; 1.1897x over previous
//
#include <hip/hip_runtime.h>
#include <hip/hip_bf16.h>

typedef __attribute__((ext_vector_type(8))) short short8;
typedef __attribute__((ext_vector_type(4))) short short4v;
typedef __attribute__((ext_vector_type(4))) float f32x4;

static __device__ __forceinline__ unsigned short f2bf(float f) {
  unsigned int u = __float_as_uint(f);
  u += 0x7fffu + ((u >> 16) & 1u);
  return (unsigned short)(u >> 16);
}

static __device__ __forceinline__ unsigned pk2bf(float a, float b) {
  union { __hip_bfloat162 h; unsigned u; } v;
  v.h = __float22bfloat162_rn(make_float2(a, b));
  return v.u;
}

static __device__ __forceinline__ void gload_lds16(const unsigned short* g,
                                                   unsigned short* l) {
  __builtin_amdgcn_global_load_lds((const __attribute__((address_space(1))) void*)g,
                                   (__attribute__((address_space(3))) void*)l, 16, 0, 0);
}

// ---------------- converts ----------------
__global__ void conv_bf16_kernel(const float* __restrict__ in,
                                 unsigned short* __restrict__ out, int n) {
  int i = (blockIdx.x * blockDim.x + threadIdx.x) * 4;
  if (i >= n) return;
  float4 v = *(const float4*)(in + i);
  short4v o;
  o[0] = (short)f2bf(v.x); o[1] = (short)f2bf(v.y);
  o[2] = (short)f2bf(v.z); o[3] = (short)f2bf(v.w);
  *(short4v*)(out + i) = o;
}

// W [K=1024,N=1024] fp32 -> Wt [N,K] bf16
__global__ void wtrans_kernel(const float* __restrict__ W,
                              unsigned short* __restrict__ Wt) {
  __shared__ float t[32][33];
  int n0 = blockIdx.x * 32, k0 = blockIdx.y * 32;
#pragma unroll
  for (int j = 0; j < 4; ++j)
    t[threadIdx.y + j * 8][threadIdx.x] =
        W[(size_t)(k0 + threadIdx.y + j * 8) * 1024 + n0 + threadIdx.x];
  __syncthreads();
#pragma unroll
  for (int j = 0; j < 4; ++j)
    Wt[(size_t)(n0 + threadIdx.y + j * 8) * 1024 + k0 + threadIdx.x] =
        f2bf(t[threadIdx.x][threadIdx.y + j * 8]);
}

// energy -> Mf (float 0/1) and Mbf (bf16 0/1)
__global__ void mask_kernel(const float* __restrict__ e, float* __restrict__ Mf,
                            unsigned short* __restrict__ Mbf, int n) {
  int i = blockIdx.x * blockDim.x + threadIdx.x;
  if (i < n) {
    float m = (fabsf(e[i]) > 0.1f) ? 1.0f : 0.0f;
    Mf[i] = m;
    Mbf[i] = f2bf(m);
  }
}

// ---------------- GEMM v3: m97 pattern + fused epilogue scale/mask ----------------
// C[M=8192,N=1024] = (X @ Wt^T + bias) * scale [* maskf row-wise for MODE 1]
template <int MODE>
__global__ __launch_bounds__(256) void gemm128_kernel(
    const unsigned short* __restrict__ X, const unsigned short* __restrict__ Wt,
    const float* __restrict__ bias, void* __restrict__ outp, float scale,
    const float* __restrict__ maskf) {
  const int K = 1024;
  __shared__ unsigned short Al[2][128 * 32];
  __shared__ unsigned short Bl[2][128 * 32];
  const int m0 = blockIdx.x * 128, n0 = blockIdx.y * 128;
  const int tid = threadIdx.x, lane = tid & 63, wid = tid >> 6;
  const int wr = wid >> 1, wc = wid & 1;
  const int g = lane >> 4, lr = lane & 15;
  const f32x4 fz = {0.f, 0.f, 0.f, 0.f};
  f32x4 acc[4][4];
#pragma unroll
  for (int i = 0; i < 4; i++)
#pragma unroll
    for (int j = 0; j < 4; j++) acc[i][j] = fz;

  const int sr0 = tid >> 2, sc0 = (tid & 3) * 8;
  const int sr1 = (256 + tid) >> 2;

  auto stage = [&](int kk, int buf) {
    gload_lds16(X + (size_t)(m0 + sr0) * K + kk + sc0, &Al[buf][wid * 512]);
    gload_lds16(X + (size_t)(m0 + sr1) * K + kk + sc0, &Al[buf][2048 + wid * 512]);
    gload_lds16(Wt + (size_t)(n0 + sr0) * K + kk + sc0, &Bl[buf][wid * 512]);
    gload_lds16(Wt + (size_t)(n0 + sr1) * K + kk + sc0, &Bl[buf][2048 + wid * 512]);
  };

  stage(0, 0);
  __syncthreads();

  int buf = 0;
  for (int k0 = 0; k0 < K; k0 += 32) {
    if (k0 < K - 32) stage(k0 + 32, buf ^ 1);
    short8 a[4], b[4];
#pragma unroll
    for (int i = 0; i < 4; i++)
      a[i] = *(const short8*)(&Al[buf][(wr * 64 + i * 16 + lr) * 32 + g * 8]);
#pragma unroll
    for (int i = 0; i < 4; i++)
      b[i] = *(const short8*)(&Bl[buf][(wc * 64 + i * 16 + lr) * 32 + g * 8]);
#pragma unroll
    for (int i = 0; i < 4; i++)
#pragma unroll
      for (int j = 0; j < 4; j++)
        acc[i][j] = __builtin_amdgcn_mfma_f32_16x16x32_bf16(a[i], b[j], acc[i][j], 0, 0, 0);
    __syncthreads();
    buf ^= 1;
  }

#pragma unroll
  for (int i = 0; i < 4; i++) {
    const int mrow0 = m0 + wr * 64 + i * 16 + g * 4;
#pragma unroll
    for (int j = 0; j < 4; j++) {
      const int ncol = n0 + wc * 64 + j * 16 + lr;
      const float bv = bias[ncol];
      if (MODE == 2) {
        float* out = (float*)outp;
#pragma unroll
        for (int e = 0; e < 4; e++)
          out[(size_t)(mrow0 + e) * 1024 + ncol] = acc[i][j][e] + bv;
      } else if (MODE == 0) {
        unsigned short* out = (unsigned short*)outp;
        const int h = ncol >> 6, dh = ncol & 63;
#pragma unroll
        for (int e = 0; e < 4; e++) {
          int mrow = mrow0 + e;
          int b_ = mrow >> 11, l = mrow & 2047;
          out[((size_t)(b_ * 16 + h) * 2048 + l) * 64 + dh] = f2bf((acc[i][j][e] + bv) * scale);
        }
      } else {
        unsigned short* out = (unsigned short*)outp;
        const int h = ncol >> 6, d = ncol & 63;
        const int b_ = mrow0 >> 11, s = mrow0 & 2047;
        const f32x4 mf = *(const f32x4*)(maskf + mrow0);  // V masked at source
        short4v pk;
#pragma unroll
        for (int e = 0; e < 4; e++) pk[e] = (short)f2bf((acc[i][j][e] + bv) * mf[e]);
        *(short4v*)(out + ((size_t)(b_ * 16 + h) * 64 + d) * 2048 + s) = pk;
      }
    }
  }
}

// ---------------- flash attention v10: native exp2, mask folded out of hot loop ----
// Qh: [B,H,L,64] bf16 PRE-SCALED by log2(e)/8; Kh: [B,H,S,64] bf16;
// Vt: [B,H,64,S] bf16 with masked-key columns zeroed; Mbf: [B,S] bf16 0/1.
// AO: [B*L,1024] bf16. Grid: 1024 blocks x 256 thr (4 waves, 32 q-rows each).
// Denominator = mfma(maskfrag, P) -> masked keys excluded; PV excludes them
// via zeroed V. Hot loop per-score VALU = ONE v_exp_f32.
__global__ __launch_bounds__(256) __attribute__((amdgpu_waves_per_eu(2, 3)))
void attn_kernel(
    const unsigned short* __restrict__ Qh, const unsigned short* __restrict__ Kh,
    const unsigned short* __restrict__ Vt, const unsigned short* __restrict__ Mbf,
    unsigned short* __restrict__ AO) {
  const int S = 2048;
  __shared__ unsigned short Lds[2][8192];  // [buf][ K:0..4095 | V:4096..8191 ]
  int bx = blockIdx.x;
  int lid = (bx & 7) * 128 + (bx >> 3);   // 8 XCDs x 128; 16 q-blocks per bh
  const int bh = lid >> 4, qbb = lid & 15;
  const int b_ = bh >> 4, h = bh & 15;
  const unsigned short* Qp = Qh + (size_t)bh * S * 64;
  const unsigned short* Kp = Kh + (size_t)bh * S * 64;
  const unsigned short* Vp = Vt + (size_t)bh * 64 * S;
  const unsigned short* Mp = Mbf + b_ * S;
  const int tid = threadIdx.x, lane = tid & 63, wid = tid >> 6;
  const int g = lane >> 4, lr = lane & 15;
  const int qbase = qbb * 128 + wid * 32;
  const f32x4 fz = {0.f, 0.f, 0.f, 0.f};

  const int srow = (lane >> 3);
  const int schk = (lane & 7) ^ srow;
  const int kr0 = wid * 16 + srow, kr1 = wid * 16 + 8 + srow;
  const int pir0 = (kr0 & 32) | ((kr0 & 12) << 1) | ((kr0 & 16) >> 2) | (kr0 & 3);
  const int pir1 = (kr1 & 32) | ((kr1 & 12) << 1) | ((kr1 & 16) >> 2) | (kr1 & 3);
  const unsigned short* gK0 = Kp + (size_t)pir0 * 64 + schk * 8;
  const unsigned short* gK1 = Kp + (size_t)pir1 * 64 + schk * 8;
  const unsigned short* gV0 = Vp + (size_t)kr0 * S + schk * 8;
  const unsigned short* gV1 = Vp + (size_t)kr1 * S + schk * 8;

  const int s7 = lr & 7;
  const int off0 = ((g ^ s7) * 8);
  const int off1 = (((4 + g) ^ s7) * 8);

  short8 qf[2][2];
#pragma unroll
  for (int qt = 0; qt < 2; qt++)
#pragma unroll
    for (int kh = 0; kh < 2; kh++)
      qf[qt][kh] = *(const short8*)(Qp + (size_t)(qbase + qt * 16 + lr) * 64 + kh * 32 + g * 8);

  f32x4 o[2][4];
  f32x4 psA[2];
#pragma unroll
  for (int qt = 0; qt < 2; qt++) {
    psA[qt] = fz;
#pragma unroll
    for (int t = 0; t < 4; t++) o[qt][t] = fz;
  }

  auto stage = [&](int s0, int buf) {
    gload_lds16(gK0 + (size_t)s0 * 64, &Lds[buf][wid * 1024]);
    gload_lds16(gK1 + (size_t)s0 * 64, &Lds[buf][wid * 1024 + 512]);
    gload_lds16(gV0 + s0, &Lds[buf][4096 + wid * 1024]);
    gload_lds16(gV1 + s0, &Lds[buf][4096 + wid * 1024 + 512]);
  };

  stage(0, 0);
  __syncthreads();

  int cur = 0;
  for (int t = 0; t < 32; ++t) {
    const int s0 = t * 64;
    if (t < 31) stage(s0 + 64, cur ^ 1);
    const unsigned short* Kb = &Lds[cur][lr * 64];
    const unsigned short* Vb = &Lds[cur][4096 + lr * 64];

    short8 kf[4][2];
#pragma unroll
    for (int st = 0; st < 4; st++) {
      kf[st][0] = *(const short8*)(Kb + st * 1024 + off0);
      kf[st][1] = *(const short8*)(Kb + st * 1024 + off1);
    }
    // 0/1 mask fragments (A-operand layout: lane (g,lr) -> keys g*8..g*8+7)
    short8 mk0 = *(const short8*)(Mp + s0 + g * 8);
    short8 mk1 = *(const short8*)(Mp + s0 + 32 + g * 8);

    union { unsigned u[8]; short8 s8[2]; } pk[2];
    __builtin_amdgcn_s_setprio(1);
#pragma unroll
    for (int qt = 0; qt < 2; qt++) {
#pragma unroll
      for (int st = 0; st < 4; st++) {
        f32x4 a0 = __builtin_amdgcn_mfma_f32_16x16x32_bf16(kf[st][0], qf[qt][0], fz, 0, 0, 0);
        f32x4 s = __builtin_amdgcn_mfma_f32_16x16x32_bf16(kf[st][1], qf[qt][1], a0, 0, 0, 0);
        f32x4 p;
#pragma unroll
        for (int e = 0; e < 4; e++) p[e] = __builtin_amdgcn_exp2f(s[e]);
        pk[qt].u[st * 2] = pk2bf(p[0], p[1]);
        pk[qt].u[st * 2 + 1] = pk2bf(p[2], p[3]);
      }
      psA[qt] = __builtin_amdgcn_mfma_f32_16x16x32_bf16(mk0, pk[qt].s8[0], psA[qt], 0, 0, 0);
      psA[qt] = __builtin_amdgcn_mfma_f32_16x16x32_bf16(mk1, pk[qt].s8[1], psA[qt], 0, 0, 0);
    }
    __builtin_amdgcn_s_setprio(0);

#pragma unroll
    for (int tt = 0; tt < 4; tt++) {
      short8 v0 = *(const short8*)(Vb + tt * 1024 + off0);
      short8 v1 = *(const short8*)(Vb + tt * 1024 + off1);
      __builtin_amdgcn_s_setprio(1);
#pragma unroll
      for (int qt = 0; qt < 2; qt++) {
        o[qt][tt] = __builtin_amdgcn_mfma_f32_16x16x32_bf16(v0, pk[qt].s8[0], o[qt][tt], 0, 0, 0);
        o[qt][tt] = __builtin_amdgcn_mfma_f32_16x16x32_bf16(v1, pk[qt].s8[1], o[qt][tt], 0, 0, 0);
      }
      __builtin_amdgcn_s_setprio(0);
    }
    __syncthreads();
    cur ^= 1;
  }

#pragma unroll
  for (int qt = 0; qt < 2; qt++) {
    float l = psA[qt][0];
    float inv = l > 0.f ? 1.f / l : 0.f;
    size_t row = (size_t)b_ * 2048 + qbase + qt * 16 + lr;
#pragma unroll
    for (int tt = 0; tt < 4; tt++) {
      unsigned lo = pk2bf(o[qt][tt][0] * inv, o[qt][tt][1] * inv);
      unsigned hi = pk2bf(o[qt][tt][2] * inv, o[qt][tt][3] * inv);
      uint2 wv; wv.x = lo; wv.y = hi;
      *(uint2*)(AO + row * 1024 + h * 64 + tt * 16 + g * 4) = wv;
    }
  }
}

// ---------------- launch ----------------
extern "C" void kernel_launch(void* const* d_in, const int* in_sizes, int n_in,
                              void* d_out, int out_size, void* d_ws, size_t ws_size,
                              hipStream_t stream) {
  const float* q_x = (const float*)d_in[0];
  const float* k_x = (const float*)d_in[1];
  const float* v_x = (const float*)d_in[2];
  const float* energy = (const float*)d_in[3];
  const float* Wq = (const float*)d_in[4];
  const float* bq = (const float*)d_in[5];
  const float* Wk = (const float*)d_in[6];
  const float* bk = (const float*)d_in[7];
  const float* Wv = (const float*)d_in[8];
  const float* bv = (const float*)d_in[9];
  const float* Wo = (const float*)d_in[10];
  const float* bo = (const float*)d_in[11];

  char* w = (char*)d_ws;
  auto take = [&](size_t bytes) {
    char* p = w;
    w += (bytes + 255) & ~(size_t)255;
    return p;
  };
  const size_t XB = (size_t)8192 * 1024 * 2;
  unsigned short* Xq = (unsigned short*)take(XB);
  unsigned short* Xk = (unsigned short*)take(XB);
  unsigned short* Xv = (unsigned short*)take(XB);
  unsigned short* Wtq = (unsigned short*)take((size_t)1024 * 1024 * 2);
  unsigned short* Wtk = (unsigned short*)take((size_t)1024 * 1024 * 2);
  unsigned short* Wtv = (unsigned short*)take((size_t)1024 * 1024 * 2);
  unsigned short* Wto = (unsigned short*)take((size_t)1024 * 1024 * 2);
  float* Mf = (float*)take((size_t)8192 * 4);
  unsigned short* Mbf = (unsigned short*)take((size_t)8192 * 2);
  unsigned short* Qh = (unsigned short*)take(XB);
  unsigned short* Kh = (unsigned short*)take(XB);
  unsigned short* Vt = (unsigned short*)take(XB);
  unsigned short* AO = (unsigned short*)take(XB);

  const float c2 = 0.18033688011f;  // log2(e)/sqrt(64)
  const int NX = 8192 * 1024;
  conv_bf16_kernel<<<NX / 1024, 256, 0, stream>>>(q_x, Xq, NX);
  conv_bf16_kernel<<<NX / 1024, 256, 0, stream>>>(k_x, Xk, NX);
  conv_bf16_kernel<<<NX / 1024, 256, 0, stream>>>(v_x, Xv, NX);
  wtrans_kernel<<<dim3(32, 32), dim3(32, 8), 0, stream>>>(Wq, Wtq);
  wtrans_kernel<<<dim3(32, 32), dim3(32, 8), 0, stream>>>(Wk, Wtk);
  wtrans_kernel<<<dim3(32, 32), dim3(32, 8), 0, stream>>>(Wv, Wtv);
  wtrans_kernel<<<dim3(32, 32), dim3(32, 8), 0, stream>>>(Wo, Wto);
  mask_kernel<<<32, 256, 0, stream>>>(energy, Mf, Mbf, 8192);

  gemm128_kernel<0><<<dim3(64, 8), 256, 0, stream>>>(Xq, Wtq, bq, (void*)Qh, c2, nullptr);
  gemm128_kernel<0><<<dim3(64, 8), 256, 0, stream>>>(Xk, Wtk, bk, (void*)Kh, 1.0f, nullptr);
  gemm128_kernel<1><<<dim3(64, 8), 256, 0, stream>>>(Xv, Wtv, bv, (void*)Vt, 1.0f, Mf);
  attn_kernel<<<1024, 256, 0, stream>>>(Qh, Kh, Vt, Mbf, AO);
  gemm128_kernel<2><<<dim3(64, 8), 256, 0, stream>>>(AO, Wto, bo, d_out, 1.0f, nullptr);
}

// Round 11
// 212.628 us; speedup vs baseline: 2.4348x; 1.0484x over previous
//
#include <hip/hip_runtime.h>
#include <hip/hip_bf16.h>

typedef __attribute__((ext_vector_type(8))) short short8;
typedef __attribute__((ext_vector_type(4))) short short4v;
typedef __attribute__((ext_vector_type(4))) float f32x4;

static __device__ __forceinline__ unsigned short f2bf(float f) {
  unsigned int u = __float_as_uint(f);
  u += 0x7fffu + ((u >> 16) & 1u);
  return (unsigned short)(u >> 16);
}

static __device__ __forceinline__ unsigned pk2bf(float a, float b) {
  union { __hip_bfloat162 h; unsigned u; } v;
  v.h = __float22bfloat162_rn(make_float2(a, b));
  return v.u;
}

static __device__ __forceinline__ void gload_lds16(const unsigned short* g,
                                                   unsigned short* l) {
  __builtin_amdgcn_global_load_lds((const __attribute__((address_space(1))) void*)g,
                                   (__attribute__((address_space(3))) void*)l, 16, 0, 0);
}

// ---------------- converts (3 inputs in one launch) ----------------
__global__ void conv3_bf16_kernel(const float* __restrict__ a, const float* __restrict__ b,
                                  const float* __restrict__ c, unsigned short* __restrict__ oa,
                                  unsigned short* __restrict__ ob, unsigned short* __restrict__ oc,
                                  int n) {
  const float* in = blockIdx.y == 0 ? a : (blockIdx.y == 1 ? b : c);
  unsigned short* out = blockIdx.y == 0 ? oa : (blockIdx.y == 1 ? ob : oc);
  int i = (blockIdx.x * blockDim.x + threadIdx.x) * 4;
  if (i >= n) return;
  float4 v = *(const float4*)(in + i);
  short4v o;
  o[0] = (short)f2bf(v.x); o[1] = (short)f2bf(v.y);
  o[2] = (short)f2bf(v.z); o[3] = (short)f2bf(v.w);
  *(short4v*)(out + i) = o;
}

// 4 weights [K,N] fp32 -> [N,K] bf16 in one launch
__global__ void wtrans4_kernel(const float* __restrict__ W0, const float* __restrict__ W1,
                               const float* __restrict__ W2, const float* __restrict__ W3,
                               unsigned short* __restrict__ T0, unsigned short* __restrict__ T1,
                               unsigned short* __restrict__ T2, unsigned short* __restrict__ T3) {
  const float* W = blockIdx.z == 0 ? W0 : (blockIdx.z == 1 ? W1 : (blockIdx.z == 2 ? W2 : W3));
  unsigned short* Wt = blockIdx.z == 0 ? T0 : (blockIdx.z == 1 ? T1 : (blockIdx.z == 2 ? T2 : T3));
  __shared__ float t[32][33];
  int n0 = blockIdx.x * 32, k0 = blockIdx.y * 32;
#pragma unroll
  for (int j = 0; j < 4; ++j)
    t[threadIdx.y + j * 8][threadIdx.x] =
        W[(size_t)(k0 + threadIdx.y + j * 8) * 1024 + n0 + threadIdx.x];
  __syncthreads();
#pragma unroll
  for (int j = 0; j < 4; ++j)
    Wt[(size_t)(n0 + threadIdx.y + j * 8) * 1024 + k0 + threadIdx.x] =
        f2bf(t[threadIdx.x][threadIdx.y + j * 8]);
}

// energy -> Mf (float 0/1) and Mbf (bf16 0/1)
__global__ void mask_kernel(const float* __restrict__ e, float* __restrict__ Mf,
                            unsigned short* __restrict__ Mbf, int n) {
  int i = blockIdx.x * blockDim.x + threadIdx.x;
  if (i < n) {
    float m = (fabsf(e[i]) > 0.1f) ? 1.0f : 0.0f;
    Mf[i] = m;
    Mbf[i] = f2bf(m);
  }
}

// ---------------- GEMM v3: m97 pattern + fused epilogue scale/mask ----------------
template <int MODE>
__global__ __launch_bounds__(256) void gemm128_kernel(
    const unsigned short* __restrict__ X, const unsigned short* __restrict__ Wt,
    const float* __restrict__ bias, void* __restrict__ outp, float scale,
    const float* __restrict__ maskf) {
  const int K = 1024;
  __shared__ unsigned short Al[2][128 * 32];
  __shared__ unsigned short Bl[2][128 * 32];
  const int m0 = blockIdx.x * 128, n0 = blockIdx.y * 128;
  const int tid = threadIdx.x, lane = tid & 63, wid = tid >> 6;
  const int wr = wid >> 1, wc = wid & 1;
  const int g = lane >> 4, lr = lane & 15;
  const f32x4 fz = {0.f, 0.f, 0.f, 0.f};
  f32x4 acc[4][4];
#pragma unroll
  for (int i = 0; i < 4; i++)
#pragma unroll
    for (int j = 0; j < 4; j++) acc[i][j] = fz;

  const int sr0 = tid >> 2, sc0 = (tid & 3) * 8;
  const int sr1 = (256 + tid) >> 2;

  auto stage = [&](int kk, int buf) {
    gload_lds16(X + (size_t)(m0 + sr0) * K + kk + sc0, &Al[buf][wid * 512]);
    gload_lds16(X + (size_t)(m0 + sr1) * K + kk + sc0, &Al[buf][2048 + wid * 512]);
    gload_lds16(Wt + (size_t)(n0 + sr0) * K + kk + sc0, &Bl[buf][wid * 512]);
    gload_lds16(Wt + (size_t)(n0 + sr1) * K + kk + sc0, &Bl[buf][2048 + wid * 512]);
  };

  stage(0, 0);
  __syncthreads();

  int buf = 0;
  for (int k0 = 0; k0 < K; k0 += 32) {
    if (k0 < K - 32) stage(k0 + 32, buf ^ 1);
    short8 a[4], b[4];
#pragma unroll
    for (int i = 0; i < 4; i++)
      a[i] = *(const short8*)(&Al[buf][(wr * 64 + i * 16 + lr) * 32 + g * 8]);
#pragma unroll
    for (int i = 0; i < 4; i++)
      b[i] = *(const short8*)(&Bl[buf][(wc * 64 + i * 16 + lr) * 32 + g * 8]);
#pragma unroll
    for (int i = 0; i < 4; i++)
#pragma unroll
      for (int j = 0; j < 4; j++)
        acc[i][j] = __builtin_amdgcn_mfma_f32_16x16x32_bf16(a[i], b[j], acc[i][j], 0, 0, 0);
    __syncthreads();
    buf ^= 1;
  }

#pragma unroll
  for (int i = 0; i < 4; i++) {
    const int mrow0 = m0 + wr * 64 + i * 16 + g * 4;
#pragma unroll
    for (int j = 0; j < 4; j++) {
      const int ncol = n0 + wc * 64 + j * 16 + lr;
      const float bv = bias[ncol];
      if (MODE == 2) {
        float* out = (float*)outp;
#pragma unroll
        for (int e = 0; e < 4; e++)
          out[(size_t)(mrow0 + e) * 1024 + ncol] = acc[i][j][e] + bv;
      } else if (MODE == 0) {
        unsigned short* out = (unsigned short*)outp;
        const int h = ncol >> 6, dh = ncol & 63;
#pragma unroll
        for (int e = 0; e < 4; e++) {
          int mrow = mrow0 + e;
          int b_ = mrow >> 11, l = mrow & 2047;
          out[((size_t)(b_ * 16 + h) * 2048 + l) * 64 + dh] = f2bf((acc[i][j][e] + bv) * scale);
        }
      } else {
        unsigned short* out = (unsigned short*)outp;
        const int h = ncol >> 6, d = ncol & 63;
        const int b_ = mrow0 >> 11, s = mrow0 & 2047;
        const f32x4 mf = *(const f32x4*)(maskf + mrow0);
        short4v pk;
#pragma unroll
        for (int e = 0; e < 4; e++) pk[e] = (short)f2bf((acc[i][j][e] + bv) * mf[e]);
        *(short4v*)(out + ((size_t)(b_ * 16 + h) * 64 + d) * 2048 + s) = pk;
      }
    }
  }
}

// ---------------- flash attention v11: v10 + full occupancy (4 blocks/CU) ----------
// Qh: [B,H,L,64] bf16 PRE-SCALED by log2(e)/8; Kh: [B,H,S,64] bf16;
// Vt: [B,H,64,S] bf16 with masked-key columns zeroed; Mbf: [B,S] bf16 0/1.
// AO: [B*L,1024] bf16. Grid: 1024 blocks x 256 thr (4 waves, 32 q-rows each).
// launch_bounds(256,4): min 4 waves/EU (VGPR cap 128; actual ~68) -> 4 blocks/CU.
__global__ __launch_bounds__(256, 4) void attn_kernel(
    const unsigned short* __restrict__ Qh, const unsigned short* __restrict__ Kh,
    const unsigned short* __restrict__ Vt, const unsigned short* __restrict__ Mbf,
    unsigned short* __restrict__ AO) {
  const int S = 2048;
  __shared__ unsigned short Lds[2][8192];  // [buf][ K:0..4095 | V:4096..8191 ]
  int bx = blockIdx.x;
  int lid = (bx & 7) * 128 + (bx >> 3);   // 8 XCDs x 128; 16 q-blocks per bh
  const int bh = lid >> 4, qbb = lid & 15;
  const int b_ = bh >> 4, h = bh & 15;
  const unsigned short* Qp = Qh + (size_t)bh * S * 64;
  const unsigned short* Kp = Kh + (size_t)bh * S * 64;
  const unsigned short* Vp = Vt + (size_t)bh * 64 * S;
  const unsigned short* Mp = Mbf + b_ * S;
  const int tid = threadIdx.x, lane = tid & 63, wid = tid >> 6;
  const int g = lane >> 4, lr = lane & 15;
  const int qbase = qbb * 128 + wid * 32;
  const f32x4 fz = {0.f, 0.f, 0.f, 0.f};

  const int srow = (lane >> 3);
  const int schk = (lane & 7) ^ srow;
  const int kr0 = wid * 16 + srow, kr1 = wid * 16 + 8 + srow;
  const int pir0 = (kr0 & 32) | ((kr0 & 12) << 1) | ((kr0 & 16) >> 2) | (kr0 & 3);
  const int pir1 = (kr1 & 32) | ((kr1 & 12) << 1) | ((kr1 & 16) >> 2) | (kr1 & 3);
  const unsigned short* gK0 = Kp + (size_t)pir0 * 64 + schk * 8;
  const unsigned short* gK1 = Kp + (size_t)pir1 * 64 + schk * 8;
  const unsigned short* gV0 = Vp + (size_t)kr0 * S + schk * 8;
  const unsigned short* gV1 = Vp + (size_t)kr1 * S + schk * 8;

  const int s7 = lr & 7;
  const int off0 = ((g ^ s7) * 8);
  const int off1 = (((4 + g) ^ s7) * 8);

  short8 qf[2][2];
#pragma unroll
  for (int qt = 0; qt < 2; qt++)
#pragma unroll
    for (int kh = 0; kh < 2; kh++)
      qf[qt][kh] = *(const short8*)(Qp + (size_t)(qbase + qt * 16 + lr) * 64 + kh * 32 + g * 8);

  f32x4 o[2][4];
  f32x4 psA[2];
#pragma unroll
  for (int qt = 0; qt < 2; qt++) {
    psA[qt] = fz;
#pragma unroll
    for (int t = 0; t < 4; t++) o[qt][t] = fz;
  }

  auto stage = [&](int s0, int buf) {
    gload_lds16(gK0 + (size_t)s0 * 64, &Lds[buf][wid * 1024]);
    gload_lds16(gK1 + (size_t)s0 * 64, &Lds[buf][wid * 1024 + 512]);
    gload_lds16(gV0 + s0, &Lds[buf][4096 + wid * 1024]);
    gload_lds16(gV1 + s0, &Lds[buf][4096 + wid * 1024 + 512]);
  };

  stage(0, 0);
  __syncthreads();

  int cur = 0;
  for (int t = 0; t < 32; ++t) {
    const int s0 = t * 64;
    if (t < 31) stage(s0 + 64, cur ^ 1);
    const unsigned short* Kb = &Lds[cur][lr * 64];
    const unsigned short* Vb = &Lds[cur][4096 + lr * 64];

    short8 kf[4][2];
#pragma unroll
    for (int st = 0; st < 4; st++) {
      kf[st][0] = *(const short8*)(Kb + st * 1024 + off0);
      kf[st][1] = *(const short8*)(Kb + st * 1024 + off1);
    }
    short8 mk0 = *(const short8*)(Mp + s0 + g * 8);
    short8 mk1 = *(const short8*)(Mp + s0 + 32 + g * 8);

    union { unsigned u[8]; short8 s8[2]; } pk[2];
    __builtin_amdgcn_s_setprio(1);
#pragma unroll
    for (int qt = 0; qt < 2; qt++) {
#pragma unroll
      for (int st = 0; st < 4; st++) {
        f32x4 a0 = __builtin_amdgcn_mfma_f32_16x16x32_bf16(kf[st][0], qf[qt][0], fz, 0, 0, 0);
        f32x4 s = __builtin_amdgcn_mfma_f32_16x16x32_bf16(kf[st][1], qf[qt][1], a0, 0, 0, 0);
        f32x4 p;
#pragma unroll
        for (int e = 0; e < 4; e++) p[e] = __builtin_amdgcn_exp2f(s[e]);
        pk[qt].u[st * 2] = pk2bf(p[0], p[1]);
        pk[qt].u[st * 2 + 1] = pk2bf(p[2], p[3]);
      }
      psA[qt] = __builtin_amdgcn_mfma_f32_16x16x32_bf16(mk0, pk[qt].s8[0], psA[qt], 0, 0, 0);
      psA[qt] = __builtin_amdgcn_mfma_f32_16x16x32_bf16(mk1, pk[qt].s8[1], psA[qt], 0, 0, 0);
    }
    __builtin_amdgcn_s_setprio(0);

#pragma unroll
    for (int tt = 0; tt < 4; tt++) {
      short8 v0 = *(const short8*)(Vb + tt * 1024 + off0);
      short8 v1 = *(const short8*)(Vb + tt * 1024 + off1);
      __builtin_amdgcn_s_setprio(1);
#pragma unroll
      for (int qt = 0; qt < 2; qt++) {
        o[qt][tt] = __builtin_amdgcn_mfma_f32_16x16x32_bf16(v0, pk[qt].s8[0], o[qt][tt], 0, 0, 0);
        o[qt][tt] = __builtin_amdgcn_mfma_f32_16x16x32_bf16(v1, pk[qt].s8[1], o[qt][tt], 0, 0, 0);
      }
      __builtin_amdgcn_s_setprio(0);
    }
    __syncthreads();
    cur ^= 1;
  }

#pragma unroll
  for (int qt = 0; qt < 2; qt++) {
    float l = psA[qt][0];
    float inv = l > 0.f ? 1.f / l : 0.f;
    size_t row = (size_t)b_ * 2048 + qbase + qt * 16 + lr;
#pragma unroll
    for (int tt = 0; tt < 4; tt++) {
      unsigned lo = pk2bf(o[qt][tt][0] * inv, o[qt][tt][1] * inv);
      unsigned hi = pk2bf(o[qt][tt][2] * inv, o[qt][tt][3] * inv);
      uint2 wv; wv.x = lo; wv.y = hi;
      *(uint2*)(AO + row * 1024 + h * 64 + tt * 16 + g * 4) = wv;
    }
  }
}

// ---------------- launch ----------------
extern "C" void kernel_launch(void* const* d_in, const int* in_sizes, int n_in,
                              void* d_out, int out_size, void* d_ws, size_t ws_size,
                              hipStream_t stream) {
  const float* q_x = (const float*)d_in[0];
  const float* k_x = (const float*)d_in[1];
  const float* v_x = (const float*)d_in[2];
  const float* energy = (const float*)d_in[3];
  const float* Wq = (const float*)d_in[4];
  const float* bq = (const float*)d_in[5];
  const float* Wk = (const float*)d_in[6];
  const float* bk = (const float*)d_in[7];
  const float* Wv = (const float*)d_in[8];
  const float* bv = (const float*)d_in[9];
  const float* Wo = (const float*)d_in[10];
  const float* bo = (const float*)d_in[11];

  char* w = (char*)d_ws;
  auto take = [&](size_t bytes) {
    char* p = w;
    w += (bytes + 255) & ~(size_t)255;
    return p;
  };
  const size_t XB = (size_t)8192 * 1024 * 2;
  unsigned short* Xq = (unsigned short*)take(XB);
  unsigned short* Xk = (unsigned short*)take(XB);
  unsigned short* Xv = (unsigned short*)take(XB);
  unsigned short* Wtq = (unsigned short*)take((size_t)1024 * 1024 * 2);
  unsigned short* Wtk = (unsigned short*)take((size_t)1024 * 1024 * 2);
  unsigned short* Wtv = (unsigned short*)take((size_t)1024 * 1024 * 2);
  unsigned short* Wto = (unsigned short*)take((size_t)1024 * 1024 * 2);
  float* Mf = (float*)take((size_t)8192 * 4);
  unsigned short* Mbf = (unsigned short*)take((size_t)8192 * 2);
  unsigned short* Qh = (unsigned short*)take(XB);
  unsigned short* Kh = (unsigned short*)take(XB);
  unsigned short* Vt = (unsigned short*)take(XB);
  unsigned short* AO = (unsigned short*)take(XB);

  const float c2 = 0.18033688011f;  // log2(e)/sqrt(64)
  const int NX = 8192 * 1024;
  conv3_bf16_kernel<<<dim3(NX / 1024, 3), 256, 0, stream>>>(q_x, k_x, v_x, Xq, Xk, Xv, NX);
  wtrans4_kernel<<<dim3(32, 32, 4), dim3(32, 8), 0, stream>>>(Wq, Wk, Wv, Wo, Wtq, Wtk, Wtv, Wto);
  mask_kernel<<<32, 256, 0, stream>>>(energy, Mf, Mbf, 8192);

  gemm128_kernel<0><<<dim3(64, 8), 256, 0, stream>>>(Xq, Wtq, bq, (void*)Qh, c2, nullptr);
  gemm128_kernel<0><<<dim3(64, 8), 256, 0, stream>>>(Xk, Wtk, bk, (void*)Kh, 1.0f, nullptr);
  gemm128_kernel<1><<<dim3(64, 8), 256, 0, stream>>>(Xv, Wtv, bv, (void*)Vt, 1.0f, Mf);
  attn_kernel<<<1024, 256, 0, stream>>>(Qh, Kh, Vt, Mbf, AO);
  gemm128_kernel<2><<<dim3(64, 8), 256, 0, stream>>>(AO, Wto, bo, d_out, 1.0f, nullptr);
}

// Round 12
// 201.840 us; speedup vs baseline: 2.5649x; 1.0535x over previous
//
#include <hip/hip_runtime.h>
#include <hip/hip_bf16.h>

typedef __attribute__((ext_vector_type(8))) short short8;
typedef __attribute__((ext_vector_type(4))) short short4v;
typedef __attribute__((ext_vector_type(4))) float f32x4;

static __device__ __forceinline__ unsigned short f2bf(float f) {
  unsigned int u = __float_as_uint(f);
  u += 0x7fffu + ((u >> 16) & 1u);
  return (unsigned short)(u >> 16);
}

// HW packed f32x2 -> bf16x2 (gfx950 v_cvt_pk_bf16_f32; no builtin exists)
static __device__ __forceinline__ unsigned cvtpk(float a, float b) {
  unsigned r;
  asm("v_cvt_pk_bf16_f32 %0, %1, %2" : "=v"(r) : "v"(a), "v"(b));
  return r;
}

static __device__ __forceinline__ void gload_lds16(const unsigned short* g,
                                                   unsigned short* l) {
  __builtin_amdgcn_global_load_lds((const __attribute__((address_space(1))) void*)g,
                                   (__attribute__((address_space(3))) void*)l, 16, 0, 0);
}

// ---------------- converts (3 inputs in one launch) ----------------
__global__ void conv3_bf16_kernel(const float* __restrict__ a, const float* __restrict__ b,
                                  const float* __restrict__ c, unsigned short* __restrict__ oa,
                                  unsigned short* __restrict__ ob, unsigned short* __restrict__ oc,
                                  int n) {
  const float* in = blockIdx.y == 0 ? a : (blockIdx.y == 1 ? b : c);
  unsigned short* out = blockIdx.y == 0 ? oa : (blockIdx.y == 1 ? ob : oc);
  int i = (blockIdx.x * blockDim.x + threadIdx.x) * 4;
  if (i >= n) return;
  float4 v = *(const float4*)(in + i);
  uint2 o;
  o.x = cvtpk(v.x, v.y);
  o.y = cvtpk(v.z, v.w);
  *(uint2*)(out + i) = o;
}

// 4 weights [K,N] fp32 -> [N,K] bf16 in one launch
__global__ void wtrans4_kernel(const float* __restrict__ W0, const float* __restrict__ W1,
                               const float* __restrict__ W2, const float* __restrict__ W3,
                               unsigned short* __restrict__ T0, unsigned short* __restrict__ T1,
                               unsigned short* __restrict__ T2, unsigned short* __restrict__ T3) {
  const float* W = blockIdx.z == 0 ? W0 : (blockIdx.z == 1 ? W1 : (blockIdx.z == 2 ? W2 : W3));
  unsigned short* Wt = blockIdx.z == 0 ? T0 : (blockIdx.z == 1 ? T1 : (blockIdx.z == 2 ? T2 : T3));
  __shared__ float t[32][33];
  int n0 = blockIdx.x * 32, k0 = blockIdx.y * 32;
#pragma unroll
  for (int j = 0; j < 4; ++j)
    t[threadIdx.y + j * 8][threadIdx.x] =
        W[(size_t)(k0 + threadIdx.y + j * 8) * 1024 + n0 + threadIdx.x];
  __syncthreads();
#pragma unroll
  for (int j = 0; j < 4; ++j)
    Wt[(size_t)(n0 + threadIdx.y + j * 8) * 1024 + k0 + threadIdx.x] =
        f2bf(t[threadIdx.x][threadIdx.y + j * 8]);
}

// energy -> Mf (float 0/1) and Mbf (bf16 0/1)
__global__ void mask_kernel(const float* __restrict__ e, float* __restrict__ Mf,
                            unsigned short* __restrict__ Mbf, int n) {
  int i = blockIdx.x * blockDim.x + threadIdx.x;
  if (i < n) {
    float m = (fabsf(e[i]) > 0.1f) ? 1.0f : 0.0f;
    Mf[i] = m;
    Mbf[i] = f2bf(m);
  }
}

// ---------------- fused QKV GEMM: one launch, grid.z selects {Q,K,V} ----------------
// z=0: Qh = (q_x@Wq+bq)*c2 -> [B,H,L,64] bf16
// z=1: Kh = (k_x@Wk+bk)     -> [B,H,S,64] bf16
// z=2: Vt = (v_x@Wv+bv)*Mf  -> [B,H,64,S] bf16 (transposed, masked)
__global__ __launch_bounds__(256, 4) void gemm_qkv_kernel(
    const unsigned short* __restrict__ Xq, const unsigned short* __restrict__ Xk,
    const unsigned short* __restrict__ Xv, const unsigned short* __restrict__ Wtq,
    const unsigned short* __restrict__ Wtk, const unsigned short* __restrict__ Wtv,
    const float* __restrict__ bq, const float* __restrict__ bk, const float* __restrict__ bv,
    unsigned short* __restrict__ Qh, unsigned short* __restrict__ Kh,
    unsigned short* __restrict__ Vt, const float* __restrict__ Mf, float c2) {
  const int K = 1024;
  __shared__ unsigned short Al[2][128 * 32];
  __shared__ unsigned short Bl[2][128 * 32];
  const int z = blockIdx.z;
  const unsigned short* X = z == 0 ? Xq : (z == 1 ? Xk : Xv);
  const unsigned short* Wt = z == 0 ? Wtq : (z == 1 ? Wtk : Wtv);
  const float* bias = z == 0 ? bq : (z == 1 ? bk : bv);
  const int m0 = blockIdx.x * 128, n0 = blockIdx.y * 128;
  const int tid = threadIdx.x, lane = tid & 63, wid = tid >> 6;
  const int wr = wid >> 1, wc = wid & 1;
  const int g = lane >> 4, lr = lane & 15;
  const f32x4 fz = {0.f, 0.f, 0.f, 0.f};
  f32x4 acc[4][4];
#pragma unroll
  for (int i = 0; i < 4; i++)
#pragma unroll
    for (int j = 0; j < 4; j++) acc[i][j] = fz;

  const int sr0 = tid >> 2, sc0 = (tid & 3) * 8;
  const int sr1 = (256 + tid) >> 2;

  auto stage = [&](int kk, int buf) {
    gload_lds16(X + (size_t)(m0 + sr0) * K + kk + sc0, &Al[buf][wid * 512]);
    gload_lds16(X + (size_t)(m0 + sr1) * K + kk + sc0, &Al[buf][2048 + wid * 512]);
    gload_lds16(Wt + (size_t)(n0 + sr0) * K + kk + sc0, &Bl[buf][wid * 512]);
    gload_lds16(Wt + (size_t)(n0 + sr1) * K + kk + sc0, &Bl[buf][2048 + wid * 512]);
  };

  stage(0, 0);
  __syncthreads();

  int buf = 0;
  for (int k0 = 0; k0 < K; k0 += 32) {
    if (k0 < K - 32) stage(k0 + 32, buf ^ 1);
    short8 a[4], b[4];
#pragma unroll
    for (int i = 0; i < 4; i++)
      a[i] = *(const short8*)(&Al[buf][(wr * 64 + i * 16 + lr) * 32 + g * 8]);
#pragma unroll
    for (int i = 0; i < 4; i++)
      b[i] = *(const short8*)(&Bl[buf][(wc * 64 + i * 16 + lr) * 32 + g * 8]);
#pragma unroll
    for (int i = 0; i < 4; i++)
#pragma unroll
      for (int j = 0; j < 4; j++)
        acc[i][j] = __builtin_amdgcn_mfma_f32_16x16x32_bf16(a[i], b[j], acc[i][j], 0, 0, 0);
    __syncthreads();
    buf ^= 1;
  }

  const float scale = (z == 0) ? c2 : 1.0f;
#pragma unroll
  for (int i = 0; i < 4; i++) {
    const int mrow0 = m0 + wr * 64 + i * 16 + g * 4;
#pragma unroll
    for (int j = 0; j < 4; j++) {
      const int ncol = n0 + wc * 64 + j * 16 + lr;
      const float bv_ = bias[ncol];
      if (z != 2) {
        unsigned short* out = z == 0 ? Qh : Kh;
        const int h = ncol >> 6, dh = ncol & 63;
#pragma unroll
        for (int e = 0; e < 4; e++) {
          int mrow = mrow0 + e;
          int b_ = mrow >> 11, l = mrow & 2047;
          out[((size_t)(b_ * 16 + h) * 2048 + l) * 64 + dh] = f2bf((acc[i][j][e] + bv_) * scale);
        }
      } else {
        const int h = ncol >> 6, d = ncol & 63;
        const int b_ = mrow0 >> 11, s = mrow0 & 2047;
        const f32x4 mf = *(const f32x4*)(Mf + mrow0);
        uint2 pk;
        pk.x = cvtpk((acc[i][j][0] + bv_) * mf[0], (acc[i][j][1] + bv_) * mf[1]);
        pk.y = cvtpk((acc[i][j][2] + bv_) * mf[2], (acc[i][j][3] + bv_) * mf[3]);
        *(uint2*)(Vt + ((size_t)(b_ * 16 + h) * 64 + d) * 2048 + s) = pk;
      }
    }
  }
}

// ---------------- output GEMM (fp32 out) ----------------
__global__ __launch_bounds__(256, 4) void gemm_out_kernel(
    const unsigned short* __restrict__ X, const unsigned short* __restrict__ Wt,
    const float* __restrict__ bias, float* __restrict__ out) {
  const int K = 1024;
  __shared__ unsigned short Al[2][128 * 32];
  __shared__ unsigned short Bl[2][128 * 32];
  const int m0 = blockIdx.x * 128, n0 = blockIdx.y * 128;
  const int tid = threadIdx.x, lane = tid & 63, wid = tid >> 6;
  const int wr = wid >> 1, wc = wid & 1;
  const int g = lane >> 4, lr = lane & 15;
  const f32x4 fz = {0.f, 0.f, 0.f, 0.f};
  f32x4 acc[4][4];
#pragma unroll
  for (int i = 0; i < 4; i++)
#pragma unroll
    for (int j = 0; j < 4; j++) acc[i][j] = fz;

  const int sr0 = tid >> 2, sc0 = (tid & 3) * 8;
  const int sr1 = (256 + tid) >> 2;

  auto stage = [&](int kk, int buf) {
    gload_lds16(X + (size_t)(m0 + sr0) * K + kk + sc0, &Al[buf][wid * 512]);
    gload_lds16(X + (size_t)(m0 + sr1) * K + kk + sc0, &Al[buf][2048 + wid * 512]);
    gload_lds16(Wt + (size_t)(n0 + sr0) * K + kk + sc0, &Bl[buf][wid * 512]);
    gload_lds16(Wt + (size_t)(n0 + sr1) * K + kk + sc0, &Bl[buf][2048 + wid * 512]);
  };

  stage(0, 0);
  __syncthreads();

  int buf = 0;
  for (int k0 = 0; k0 < K; k0 += 32) {
    if (k0 < K - 32) stage(k0 + 32, buf ^ 1);
    short8 a[4], b[4];
#pragma unroll
    for (int i = 0; i < 4; i++)
      a[i] = *(const short8*)(&Al[buf][(wr * 64 + i * 16 + lr) * 32 + g * 8]);
#pragma unroll
    for (int i = 0; i < 4; i++)
      b[i] = *(const short8*)(&Bl[buf][(wc * 64 + i * 16 + lr) * 32 + g * 8]);
#pragma unroll
    for (int i = 0; i < 4; i++)
#pragma unroll
      for (int j = 0; j < 4; j++)
        acc[i][j] = __builtin_amdgcn_mfma_f32_16x16x32_bf16(a[i], b[j], acc[i][j], 0, 0, 0);
    __syncthreads();
    buf ^= 1;
  }

#pragma unroll
  for (int i = 0; i < 4; i++) {
    const int mrow0 = m0 + wr * 64 + i * 16 + g * 4;
#pragma unroll
    for (int j = 0; j < 4; j++) {
      const int ncol = n0 + wc * 64 + j * 16 + lr;
      const float bv = bias[ncol];
#pragma unroll
      for (int e = 0; e < 4; e++)
        out[(size_t)(mrow0 + e) * 1024 + ncol] = acc[i][j][e] + bv;
    }
  }
}

// ---------------- flash attention v12: v11 + HW cvt_pk ----------------
// Qh: [B,H,L,64] bf16 PRE-SCALED by log2(e)/8; Kh: [B,H,S,64] bf16;
// Vt: [B,H,64,S] bf16 with masked-key columns zeroed; Mbf: [B,S] bf16 0/1.
// AO: [B*L,1024] bf16. Grid: 1024 blocks x 256 thr (4 waves, 32 q-rows each).
__global__ __launch_bounds__(256, 4) void attn_kernel(
    const unsigned short* __restrict__ Qh, const unsigned short* __restrict__ Kh,
    const unsigned short* __restrict__ Vt, const unsigned short* __restrict__ Mbf,
    unsigned short* __restrict__ AO) {
  const int S = 2048;
  __shared__ unsigned short Lds[2][8192];  // [buf][ K:0..4095 | V:4096..8191 ]
  int bx = blockIdx.x;
  int lid = (bx & 7) * 128 + (bx >> 3);   // 8 XCDs x 128; 16 q-blocks per bh
  const int bh = lid >> 4, qbb = lid & 15;
  const int b_ = bh >> 4, h = bh & 15;
  const unsigned short* Qp = Qh + (size_t)bh * S * 64;
  const unsigned short* Kp = Kh + (size_t)bh * S * 64;
  const unsigned short* Vp = Vt + (size_t)bh * 64 * S;
  const unsigned short* Mp = Mbf + b_ * S;
  const int tid = threadIdx.x, lane = tid & 63, wid = tid >> 6;
  const int g = lane >> 4, lr = lane & 15;
  const int qbase = qbb * 128 + wid * 32;
  const f32x4 fz = {0.f, 0.f, 0.f, 0.f};

  const int srow = (lane >> 3);
  const int schk = (lane & 7) ^ srow;
  const int kr0 = wid * 16 + srow, kr1 = wid * 16 + 8 + srow;
  const int pir0 = (kr0 & 32) | ((kr0 & 12) << 1) | ((kr0 & 16) >> 2) | (kr0 & 3);
  const int pir1 = (kr1 & 32) | ((kr1 & 12) << 1) | ((kr1 & 16) >> 2) | (kr1 & 3);
  const unsigned short* gK0 = Kp + (size_t)pir0 * 64 + schk * 8;
  const unsigned short* gK1 = Kp + (size_t)pir1 * 64 + schk * 8;
  const unsigned short* gV0 = Vp + (size_t)kr0 * S + schk * 8;
  const unsigned short* gV1 = Vp + (size_t)kr1 * S + schk * 8;

  const int s7 = lr & 7;
  const int off0 = ((g ^ s7) * 8);
  const int off1 = (((4 + g) ^ s7) * 8);

  short8 qf[2][2];
#pragma unroll
  for (int qt = 0; qt < 2; qt++)
#pragma unroll
    for (int kh = 0; kh < 2; kh++)
      qf[qt][kh] = *(const short8*)(Qp + (size_t)(qbase + qt * 16 + lr) * 64 + kh * 32 + g * 8);

  f32x4 o[2][4];
  f32x4 psA[2];
#pragma unroll
  for (int qt = 0; qt < 2; qt++) {
    psA[qt] = fz;
#pragma unroll
    for (int t = 0; t < 4; t++) o[qt][t] = fz;
  }

  auto stage = [&](int s0, int buf) {
    gload_lds16(gK0 + (size_t)s0 * 64, &Lds[buf][wid * 1024]);
    gload_lds16(gK1 + (size_t)s0 * 64, &Lds[buf][wid * 1024 + 512]);
    gload_lds16(gV0 + s0, &Lds[buf][4096 + wid * 1024]);
    gload_lds16(gV1 + s0, &Lds[buf][4096 + wid * 1024 + 512]);
  };

  stage(0, 0);
  __syncthreads();

  int cur = 0;
  for (int t = 0; t < 32; ++t) {
    const int s0 = t * 64;
    if (t < 31) stage(s0 + 64, cur ^ 1);
    const unsigned short* Kb = &Lds[cur][lr * 64];
    const unsigned short* Vb = &Lds[cur][4096 + lr * 64];

    short8 kf[4][2];
#pragma unroll
    for (int st = 0; st < 4; st++) {
      kf[st][0] = *(const short8*)(Kb + st * 1024 + off0);
      kf[st][1] = *(const short8*)(Kb + st * 1024 + off1);
    }
    short8 mk0 = *(const short8*)(Mp + s0 + g * 8);
    short8 mk1 = *(const short8*)(Mp + s0 + 32 + g * 8);

    union { unsigned u[8]; short8 s8[2]; } pk[2];
    __builtin_amdgcn_s_setprio(1);
#pragma unroll
    for (int qt = 0; qt < 2; qt++) {
#pragma unroll
      for (int st = 0; st < 4; st++) {
        f32x4 a0 = __builtin_amdgcn_mfma_f32_16x16x32_bf16(kf[st][0], qf[qt][0], fz, 0, 0, 0);
        f32x4 s = __builtin_amdgcn_mfma_f32_16x16x32_bf16(kf[st][1], qf[qt][1], a0, 0, 0, 0);
        f32x4 p;
#pragma unroll
        for (int e = 0; e < 4; e++) p[e] = __builtin_amdgcn_exp2f(s[e]);
        pk[qt].u[st * 2] = cvtpk(p[0], p[1]);
        pk[qt].u[st * 2 + 1] = cvtpk(p[2], p[3]);
      }
      psA[qt] = __builtin_amdgcn_mfma_f32_16x16x32_bf16(mk0, pk[qt].s8[0], psA[qt], 0, 0, 0);
      psA[qt] = __builtin_amdgcn_mfma_f32_16x16x32_bf16(mk1, pk[qt].s8[1], psA[qt], 0, 0, 0);
    }
    __builtin_amdgcn_s_setprio(0);

#pragma unroll
    for (int tt = 0; tt < 4; tt++) {
      short8 v0 = *(const short8*)(Vb + tt * 1024 + off0);
      short8 v1 = *(const short8*)(Vb + tt * 1024 + off1);
      __builtin_amdgcn_s_setprio(1);
#pragma unroll
      for (int qt = 0; qt < 2; qt++) {
        o[qt][tt] = __builtin_amdgcn_mfma_f32_16x16x32_bf16(v0, pk[qt].s8[0], o[qt][tt], 0, 0, 0);
        o[qt][tt] = __builtin_amdgcn_mfma_f32_16x16x32_bf16(v1, pk[qt].s8[1], o[qt][tt], 0, 0, 0);
      }
      __builtin_amdgcn_s_setprio(0);
    }
    __syncthreads();
    cur ^= 1;
  }

#pragma unroll
  for (int qt = 0; qt < 2; qt++) {
    float l = psA[qt][0];
    float inv = l > 0.f ? 1.f / l : 0.f;
    size_t row = (size_t)b_ * 2048 + qbase + qt * 16 + lr;
#pragma unroll
    for (int tt = 0; tt < 4; tt++) {
      uint2 wv;
      wv.x = cvtpk(o[qt][tt][0] * inv, o[qt][tt][1] * inv);
      wv.y = cvtpk(o[qt][tt][2] * inv, o[qt][tt][3] * inv);
      *(uint2*)(AO + row * 1024 + h * 64 + tt * 16 + g * 4) = wv;
    }
  }
}

// ---------------- launch ----------------
extern "C" void kernel_launch(void* const* d_in, const int* in_sizes, int n_in,
                              void* d_out, int out_size, void* d_ws, size_t ws_size,
                              hipStream_t stream) {
  const float* q_x = (const float*)d_in[0];
  const float* k_x = (const float*)d_in[1];
  const float* v_x = (const float*)d_in[2];
  const float* energy = (const float*)d_in[3];
  const float* Wq = (const float*)d_in[4];
  const float* bq = (const float*)d_in[5];
  const float* Wk = (const float*)d_in[6];
  const float* bk = (const float*)d_in[7];
  const float* Wv = (const float*)d_in[8];
  const float* bv = (const float*)d_in[9];
  const float* Wo = (const float*)d_in[10];
  const float* bo = (const float*)d_in[11];

  char* w = (char*)d_ws;
  auto take = [&](size_t bytes) {
    char* p = w;
    w += (bytes + 255) & ~(size_t)255;
    return p;
  };
  const size_t XB = (size_t)8192 * 1024 * 2;
  unsigned short* Xq = (unsigned short*)take(XB);
  unsigned short* Xk = (unsigned short*)take(XB);
  unsigned short* Xv = (unsigned short*)take(XB);
  unsigned short* Wtq = (unsigned short*)take((size_t)1024 * 1024 * 2);
  unsigned short* Wtk = (unsigned short*)take((size_t)1024 * 1024 * 2);
  unsigned short* Wtv = (unsigned short*)take((size_t)1024 * 1024 * 2);
  unsigned short* Wto = (unsigned short*)take((size_t)1024 * 1024 * 2);
  float* Mf = (float*)take((size_t)8192 * 4);
  unsigned short* Mbf = (unsigned short*)take((size_t)8192 * 2);
  unsigned short* Qh = (unsigned short*)take(XB);
  unsigned short* Kh = (unsigned short*)take(XB);
  unsigned short* Vt = (unsigned short*)take(XB);
  unsigned short* AO = (unsigned short*)take(XB);

  const float c2 = 0.18033688011f;  // log2(e)/sqrt(64)
  const int NX = 8192 * 1024;
  conv3_bf16_kernel<<<dim3(NX / 1024, 3), 256, 0, stream>>>(q_x, k_x, v_x, Xq, Xk, Xv, NX);
  wtrans4_kernel<<<dim3(32, 32, 4), dim3(32, 8), 0, stream>>>(Wq, Wk, Wv, Wo, Wtq, Wtk, Wtv, Wto);
  mask_kernel<<<32, 256, 0, stream>>>(energy, Mf, Mbf, 8192);

  gemm_qkv_kernel<<<dim3(64, 8, 3), 256, 0, stream>>>(Xq, Xk, Xv, Wtq, Wtk, Wtv,
                                                      bq, bk, bv, Qh, Kh, Vt, Mf, c2);
  attn_kernel<<<1024, 256, 0, stream>>>(Qh, Kh, Vt, Mbf, AO);
  gemm_out_kernel<<<dim3(64, 8), 256, 0, stream>>>(AO, Wto, bo, (float*)d_out);
}